// Round 7
// baseline (744.204 us; speedup 1.0000x reference)
//
#include <hip/hip_runtime.h>

// ---------------------------------------------------------------------------
// DoshaGAT: 3-layer GAT. R11 (= R10 +):
//  - Degree-sorted node order (counting sort, 64 clamped buckets, built once,
//    shared by both aggs): waves group similar-degree nodes -> uniform-trip
//    edge loop padding drops ~45% -> ~3%.
//  - agg edge loop unroll 4 (deeper memory pipeline vs ~200cy L2 latency).
//  - alpha_kernel single-pass: exp stash in 4 named regs (deg<=64 fast path,
//    wave-uniform block guards; residual recompute loop for deg>64).
//  - R10 kept: 8 nodes x 8 feat-lanes sliced agg, slice-major h, XCD %8,
//    folded BN, nt stores, GEMM/l3 verbatim.
// ---------------------------------------------------------------------------

#define WSZ 64

typedef short short8 __attribute__((ext_vector_type(8)));
typedef short short4v __attribute__((ext_vector_type(4)));
typedef float float4v __attribute__((ext_vector_type(4)));
typedef float f2v __attribute__((ext_vector_type(2)));
typedef unsigned uint2v __attribute__((ext_vector_type(2)));

__device__ inline unsigned short f2bf(float f) {  // RNE f32->bf16
  unsigned u = __float_as_uint(f);
  u += 0x7FFFu + ((u >> 16) & 1u);
  return (unsigned short)(u >> 16);
}
__device__ inline float bf2f(unsigned short u) {
  return __uint_as_float(((unsigned)u) << 16);
}

// ---------------- CSR build ----------------

__global__ __launch_bounds__(256) void hist_kernel(const int* __restrict__ dst, int E,
                                                   int* __restrict__ deg) {
  int e = blockIdx.x * 256 + threadIdx.x;
  if (e < E) atomicAdd(&deg[dst[e]], 1);
}

__global__ __launch_bounds__(256) void block_sums_kernel(const int* __restrict__ deg, int n,
                                                         int* __restrict__ bsum) {
  __shared__ int sh[256];
  int t = threadIdx.x;
  int base = blockIdx.x * 1024 + t * 4;
  int v = 0;
#pragma unroll
  for (int j = 0; j < 4; ++j) {
    int idx = base + j;
    if (idx < n) v += deg[idx];
  }
  sh[t] = v;
  __syncthreads();
  for (int off = 128; off >= 1; off >>= 1) {
    if (t < off) sh[t] += sh[t + off];
    __syncthreads();
  }
  if (t == 0) bsum[blockIdx.x] = sh[0];
}

__global__ void tiny_scan_kernel(int* bsum, int nb) {
  if (threadIdx.x == 0 && blockIdx.x == 0) {
    int run = 0;
    for (int i = 0; i < nb; ++i) {
      int v = bsum[i];
      bsum[i] = run;
      run += v;
    }
  }
}

__global__ __launch_bounds__(256) void scan_write_kernel(const int* __restrict__ deg, int n,
                                                         const int* __restrict__ bbase,
                                                         int* __restrict__ row_start,
                                                         int* __restrict__ cursor) {
  __shared__ int sh[256];
  int t = threadIdx.x;
  int base = blockIdx.x * 1024 + t * 4;
  int v[4];
  int s = 0;
#pragma unroll
  for (int j = 0; j < 4; ++j) {
    int idx = base + j;
    v[j] = (idx < n) ? deg[idx] : 0;
    s += v[j];
  }
  sh[t] = s;
  __syncthreads();
  for (int off = 1; off < 256; off <<= 1) {
    int x = (t >= off) ? sh[t - off] : 0;
    __syncthreads();
    sh[t] += x;
    __syncthreads();
  }
  int excl = sh[t] - s + bbase[blockIdx.x];
#pragma unroll
  for (int j = 0; j < 4; ++j) {
    int idx = base + j;
    if (idx < n) {
      row_start[idx] = excl;
      cursor[idx] = excl;
    }
    excl += v[j];
  }
  if (blockIdx.x == gridDim.x - 1 && t == 255) row_start[n] = excl;  // == E
}

__global__ __launch_bounds__(256) void scatter_kernel(const int* __restrict__ src,
                                                      const int* __restrict__ dst, int E,
                                                      int* __restrict__ cursor,
                                                      int* __restrict__ csr_src) {
  int e = blockIdx.x * 256 + threadIdx.x;
  if (e < E) {
    int d = dst[e];
    int p = atomicAdd(&cursor[d], 1);
    csr_src[p] = src[e];
  }
}

// ---------------- degree sort (counting sort, 64 clamped buckets) -----------

__global__ __launch_bounds__(256) void dhist_kernel(const int* __restrict__ deg, int N,
                                                    int* __restrict__ dh) {
  int n = blockIdx.x * 256 + threadIdx.x;
  if (n < N) atomicAdd(&dh[min(deg[n], 63)], 1);
}

__global__ void dscan_kernel(const int* __restrict__ dh, int* __restrict__ dcur,
                             int* __restrict__ nodeord, int N) {
  if (threadIdx.x == 0) {
    int run = 0;
    for (int i = 0; i < 64; ++i) {
      dcur[i] = run;
      run += dh[i];
    }
  }
  nodeord[N + threadIdx.x] = 0;  // pad (64 threads)
}

__global__ __launch_bounds__(256) void dscatter_kernel(const int* __restrict__ deg, int N,
                                                       int* __restrict__ dcur,
                                                       int* __restrict__ nodeord) {
  int n = blockIdx.x * 256 + threadIdx.x;
  if (n < N) {
    int p = atomicAdd(&dcur[min(deg[n], 63)], 1);
    nodeord[p] = n;
  }
}

// ---------------- weight conversion + BN fold ----------------

// W1 [128][256] -> W1t [256][128] bf16
__global__ __launch_bounds__(256) void conv_w1t_kernel(const float* __restrict__ W1,
                                                       unsigned short* __restrict__ W1t) {
  int idx = blockIdx.x * 256 + threadIdx.x;  // 32768
  int n = idx >> 7, k = idx & 127;
  W1t[idx] = f2bf(W1[k * 256 + n]);
}

// W2 [256][128] -> W2t [128][256] bf16, K rows permuted to layer-1 phys layout
__global__ __launch_bounds__(256) void conv_w2t_kernel(const float* __restrict__ W2,
                                                       unsigned short* __restrict__ W2t) {
  int idx = blockIdx.x * 256 + threadIdx.x;  // 32768
  int n = idx >> 8, p = idx & 255;
  int kl = (p & ~63) | ((p & 3) << 4) | ((p >> 2) & 15);
  W2t[idx] = f2bf(W2[kl * 128 + n]);
}

// fold bias+BN into per-logical-col scale/shift: o*sc + sh
__global__ __launch_bounds__(512) void bn_prep_kernel(
    const float* __restrict__ b1, const float* __restrict__ g1,
    const float* __restrict__ be1, const float* __restrict__ m1,
    const float* __restrict__ v1, const float* __restrict__ b2,
    const float* __restrict__ g2, const float* __restrict__ be2,
    const float* __restrict__ m2, const float* __restrict__ v2,
    float* __restrict__ sc1, float* __restrict__ sh1,
    float* __restrict__ sc2, float* __restrict__ sh2) {
  int t = threadIdx.x;
  if (t < 256) {
    float s = g1[t] * rsqrtf(v1[t] + 1e-5f);
    sc1[t] = s;
    sh1[t] = (b1[t] - m1[t]) * s + be1[t];
  } else if (t < 384) {
    int i = t - 256;
    float s = g2[i] * rsqrtf(v2[i] + 1e-5f);
    sc2[i] = s;
    sh2[i] = (b2[i] - m2[i]) * s + be2[i];
  }
}

// ---------------- bf16 MFMA GEMM + fused attn-coeff epilogue ----------------
// C[M,BN] = A[M,K] @ B[K,BN]. 64-row blocks, 256 threads, 4 waves (wave=head).
// AF32: A is f32, converted to bf16 during LDS staging.
// hout is written SLICE-MAJOR: 8 subtables of [M][BN/8] bf16.

template <int K, int BN, bool AF32>
__global__ __launch_bounds__(256) void gemm_mfma(
    const void* __restrict__ Ap,            // [M][K] bf16 or f32
    const unsigned short* __restrict__ Bt,  // [BN][K] bf16 (pre-transposed)
    const float* __restrict__ a_s, const float* __restrict__ a_d,  // [BN] logical
    unsigned short* __restrict__ hout,      // slice-major output
    float* __restrict__ als, float* __restrict__ ald,  // [M][4]
    int M) {
  constexpr int CF = BN / 64;  // col frags per wave
  constexpr int SF = BN / 8;   // feats per slice (32 or 16)
  constexpr int PAD = 36;
  __shared__ unsigned short As[64][PAD];
  __shared__ unsigned short Bs[BN][PAD];
  const int t = threadIdx.x;
  const int w = t >> 6;
  const int lane = t & 63;
  const int c16 = lane & 15;
  const int q = lane >> 4;
  const int bm = blockIdx.x * 64;
  const int arow = t >> 2;      // 0..63
  const int akc = (t & 3) * 8;  // 0,8,16,24

  float4v acc[4][CF];
#pragma unroll
  for (int rf = 0; rf < 4; ++rf)
#pragma unroll
    for (int cf = 0; cf < CF; ++cf) acc[rf][cf] = float4v{0.f, 0.f, 0.f, 0.f};

  for (int k0 = 0; k0 < K; k0 += 32) {
    {  // stage A tile 64x32 (8 elems/thread)
      int gr = bm + arow;
      if constexpr (AF32) {
        const float* Af = (const float*)Ap + (size_t)gr * K + k0 + akc;
        float4 v0 = make_float4(0.f, 0.f, 0.f, 0.f), v1 = v0;
        if (gr < M) {
          v0 = *(const float4*)Af;
          v1 = *(const float4*)(Af + 4);
        }
        ushort4 u0, u1;
        u0.x = f2bf(v0.x); u0.y = f2bf(v0.y); u0.z = f2bf(v0.z); u0.w = f2bf(v0.w);
        u1.x = f2bf(v1.x); u1.y = f2bf(v1.y); u1.z = f2bf(v1.z); u1.w = f2bf(v1.w);
        *(ushort4*)&As[arow][akc] = u0;
        *(ushort4*)&As[arow][akc + 4] = u1;
      } else {
        uint4 v = make_uint4(0u, 0u, 0u, 0u);
        if (gr < M) v = *(const uint4*)((const unsigned short*)Ap + (size_t)gr * K + k0 + akc);
        *(uint2*)&As[arow][akc] = make_uint2(v.x, v.y);
        *(uint2*)&As[arow][akc + 4] = make_uint2(v.z, v.w);
      }
    }
#pragma unroll
    for (int h = 0; h < BN / 64; ++h) {  // stage B tile BNx32
      int n = (t >> 2) + h * 64;
      uint4 v = *(const uint4*)(Bt + (size_t)n * K + k0 + akc);
      *(uint2*)&Bs[n][akc] = make_uint2(v.x, v.y);
      *(uint2*)&Bs[n][akc + 4] = make_uint2(v.z, v.w);
    }
    __syncthreads();
    short8 af[4], bfr[CF];
#pragma unroll
    for (int rf = 0; rf < 4; ++rf) {
      short4v lo = *(short4v*)&As[rf * 16 + c16][q * 8];
      short4v hi = *(short4v*)&As[rf * 16 + c16][q * 8 + 4];
      af[rf] = __builtin_shufflevector(lo, hi, 0, 1, 2, 3, 4, 5, 6, 7);
    }
#pragma unroll
    for (int cf = 0; cf < CF; ++cf) {
      int n = w * (CF * 16) + cf * 16 + c16;
      short4v lo = *(short4v*)&Bs[n][q * 8];
      short4v hi = *(short4v*)&Bs[n][q * 8 + 4];
      bfr[cf] = __builtin_shufflevector(lo, hi, 0, 1, 2, 3, 4, 5, 6, 7);
    }
#pragma unroll
    for (int rf = 0; rf < 4; ++rf)
#pragma unroll
      for (int cf = 0; cf < CF; ++cf)
        acc[rf][cf] =
            __builtin_amdgcn_mfma_f32_16x16x32_bf16(af[rf], bfr[cf], acc[rf][cf], 0, 0, 0);
    __syncthreads();
  }

  float sasv[CF], sadv[CF];
#pragma unroll
  for (int cf = 0; cf < CF; ++cf) {
    int L = w * (CF * 16) + cf * 16 + c16;
    sasv[cf] = a_s[L];
    sadv[cf] = a_d[L];
  }
  // slice-major store base: subtable = w*2 + (c16>>3)
  const size_t sub = (size_t)(w * 2 + (c16 >> 3)) * (size_t)M * SF;
#pragma unroll
  for (int rf = 0; rf < 4; ++rf) {
#pragma unroll
    for (int r = 0; r < 4; ++r) {
      int n = bm + rf * 16 + q * 4 + r;
      float ps = 0.f, pd = 0.f;
      unsigned short us[CF];
#pragma unroll
      for (int cf = 0; cf < CF; ++cf) {
        float v = acc[rf][cf][r];
        us[cf] = f2bf(v);
        ps += v * sasv[cf];
        pd += v * sadv[cf];
      }
#pragma unroll
      for (int off = 1; off <= 8; off <<= 1) {
        ps += __shfl_xor(ps, off, 16);
        pd += __shfl_xor(pd, off, 16);
      }
      if (n < M) {
        if constexpr (CF == 4) {
          ushort4 u;
          u.x = us[0]; u.y = us[1]; u.z = us[2]; u.w = us[3];
          *(ushort4*)(hout + sub + (size_t)n * 32 + (c16 & 7) * 4) = u;
        } else {
          ushort2 u;
          u.x = us[0]; u.y = us[1];
          *(ushort2*)(hout + sub + (size_t)n * 16 + (c16 & 7) * 2) = u;
        }
        if (c16 == 0) {
          als[(size_t)n * 4 + w] = ps;
          ald[(size_t)n * 4 + w] = pd;
        }
      }
    }
  }
}

// ---------------- alpha precompute (single-pass, reg-stashed exp) -----------
// Wave per node; lanes = 16 edge-slots x 4 heads. Fast path deg<=64 keeps the
// 4 exp values in named regs; residual loop (deg>64) recomputes. Block guards
// are wave-uniform (row/end scalar) -> cheap skips.

__global__ __launch_bounds__(256) void alpha_kernel(
    const float* __restrict__ als, const float* __restrict__ ald,
    const int* __restrict__ row_start, const int* __restrict__ csr_src,
    float* __restrict__ alpha, int E, int n_nodes) {
  int wid = threadIdx.x >> 6, lane = threadIdx.x & 63;
  int n = __builtin_amdgcn_readfirstlane(blockIdx.x * 4 + wid);
  if (n >= n_nodes) return;
  int head = lane & 3;
  int eg = lane >> 2;  // 16 edge slots
  float aldv = ald[(size_t)n * 4 + head];
  int row = __builtin_amdgcn_readfirstlane(row_start[n]);
  int end = __builtin_amdgcn_readfirstlane(row_start[n + 1]);
  float ex0 = 0.f, ex1 = 0.f, ex2 = 0.f, ex3 = 0.f;

#define ABLK(exK, base)                                             \
  {                                                                 \
    int e = (base) + eg;                                            \
    int ec = (e < end) ? e : (end - 1);                             \
    int s = csr_src[ec];                                            \
    float xv = als[(size_t)(unsigned)s * 4 + head] + aldv;          \
    xv = fmaxf(xv, 0.2f * xv);                                      \
    exK = (e < end) ? __expf(xv) : 0.f;                             \
  }

  ABLK(ex0, row)
  if (end > row + 16) ABLK(ex1, row + 16)
  if (end > row + 32) ABLK(ex2, row + 32)
  if (end > row + 48) ABLK(ex3, row + 48)
  float ssum = (ex0 + ex1) + (ex2 + ex3);
  for (int i = row + 64; i < end; i += 16) {  // residual (deg > 64, rare)
    int e = i + eg;
    int ec = (e < end) ? e : (end - 1);
    int s = csr_src[ec];
    float xv = als[(size_t)(unsigned)s * 4 + head] + aldv;
    xv = fmaxf(xv, 0.2f * xv);
    ssum += (e < end) ? __expf(xv) : 0.f;
  }
  ssum += __shfl_xor(ssum, 4, 64);
  ssum += __shfl_xor(ssum, 8, 64);
  ssum += __shfl_xor(ssum, 16, 64);
  ssum += __shfl_xor(ssum, 32, 64);
  float inv = 1.f / (ssum + 1e-16f);
  float* apl = alpha + (size_t)head * (unsigned)E;
  if (row + eg < end) apl[row + eg] = ex0 * inv;
  if (end > row + 16 && row + 16 + eg < end) apl[row + 16 + eg] = ex1 * inv;
  if (end > row + 32 && row + 32 + eg < end) apl[row + 32 + eg] = ex2 * inv;
  if (end > row + 48 && row + 48 + eg < end) apl[row + 48 + eg] = ex3 * inv;
  for (int i = row + 64; i < end; i += 16) {  // residual pass B
    int e = i + eg;
    if (e < end) {
      int s = csr_src[e];
      float xv = als[(size_t)(unsigned)s * 4 + head] + aldv;
      xv = fmaxf(xv, 0.2f * xv);
      apl[e] = __expf(xv) * inv;
    }
  }
#undef ABLK
}

// ---------------- XCD-sliced GAT aggregation (8 sorted nodes/wave) ----------
// slice = blockIdx%8 -> XCD affinity; per-XCD h working set 3.2MB/1.6MB (L2).
// Wave = 8 degree-sorted nodes x 8 feat-lanes; uniform wave-max loop (sorted
// -> minimal padding), unroll 4 for memory-level parallelism. BN pre-folded.

template <int D>
__global__ __launch_bounds__(256) void gat_agg_slice(
    const unsigned short* __restrict__ h_sl,  // 8 slice-major subtables
    const float* __restrict__ alpha,          // [4][E]
    const int* __restrict__ row_start, const int* __restrict__ csr_src,
    const int* __restrict__ nodeord,          // degree-sorted, padded
    const float* __restrict__ bnsc, const float* __restrict__ bnsh,  // [D] logical
    unsigned short* __restrict__ obf,  // D==256 out (bf16 phys rows)
    float* __restrict__ of32,          // D==128 out (f32 phys rows)
    int E, int n_nodes) {
  constexpr int SFEAT = D / 8;   // 32 | 16
  constexpr int KF = SFEAT / 8;  // feats per lane: 4 | 2
  const int sl = blockIdx.x & 7;
  const int g = blockIdx.x >> 3;
  const int wid = threadIdx.x >> 6, lane = threadIdx.x & 63;
  const int f = lane & 7;    // feat slot
  const int ng = lane >> 3;  // node sub-slot 0..7
  const int head = sl >> 1;
  const char* hb = (const char*)(h_sl + (size_t)sl * (unsigned)n_nodes * SFEAT);
  const char* cb = (const char*)csr_src;
  const char* apb = (const char*)(alpha + (size_t)head * (unsigned)E);
  const unsigned uoff = (unsigned)(f * KF * 2);  // byte off in slice row

  // folded BN constants for this lane's logical cols (independent of node)
  const int lb = (D == 256 ? head * 64 : head * 32) + (sl & 1) * 8 + f;
  float sc0 = bnsc[lb], sh0 = bnsh[lb];
  float sc1 = bnsc[lb + 16], sh1 = bnsh[lb + 16];
  float sc2 = 0.f, sh2 = 0.f, sc3 = 0.f, sh3 = 0.f;
  if constexpr (D == 256) {
    sc2 = bnsc[lb + 32]; sh2 = bnsh[lb + 32];
    sc3 = bnsc[lb + 48]; sh3 = bnsh[lb + 48];
  }

  int slot = g * 32 + wid * 8 + ng;
  bool valid = slot < n_nodes;
  int n = nodeord[slot];  // padded past n_nodes with 0
  int row = row_start[n];
  int deg = row_start[n + 1] - row;
  if (!valid) deg = 0;
  // wave-max degree (ng lives in lane bits 3..5)
  int mx = deg;
#pragma unroll
  for (int off = 8; off <= 32; off <<= 1) mx = max(mx, __shfl_xor(mx, off, 64));
  mx = __builtin_amdgcn_readfirstlane(mx);

  float acc0 = 0.f, acc1 = 0.f, acc2 = 0.f, acc3 = 0.f;
#pragma unroll 4
  for (int j = 0; j < mx; ++j) {
    bool act = j < deg;
    unsigned idx = (unsigned)(row + (act ? j : 0));
    int s = *(const int*)(cb + idx * 4u);
    float a = *(const float*)(apb + idx * 4u);
    a = act ? a : 0.f;
    if constexpr (D == 256) {
      uint2v u = *(const uint2v*)(hb + ((unsigned)s * 64u + uoff));
      acc0 += a * __uint_as_float(u.x << 16);
      acc1 += a * __uint_as_float(u.x & 0xffff0000u);
      acc2 += a * __uint_as_float(u.y << 16);
      acc3 += a * __uint_as_float(u.y & 0xffff0000u);
    } else {
      unsigned u = *(const unsigned*)(hb + ((unsigned)s * 32u + uoff));
      acc0 += a * __uint_as_float(u << 16);
      acc1 += a * __uint_as_float(u & 0xffff0000u);
    }
  }

  if (valid) {
    if constexpr (D == 256) {
      float v0 = acc0 * sc0 + sh0;
      float v1 = acc1 * sc1 + sh1;
      float v2 = acc2 * sc2 + sh2;
      float v3 = acc3 * sc3 + sh3;
      v0 = (v0 > 0.f) ? v0 : (__expf(v0) - 1.f);
      v1 = (v1 > 0.f) ? v1 : (__expf(v1) - 1.f);
      v2 = (v2 > 0.f) ? v2 : (__expf(v2) - 1.f);
      v3 = (v3 > 0.f) ? v3 : (__expf(v3) - 1.f);
      uint2v pk;
      pk.x = (unsigned)f2bf(v0) | ((unsigned)f2bf(v1) << 16);
      pk.y = (unsigned)f2bf(v2) | ((unsigned)f2bf(v3) << 16);
      __builtin_nontemporal_store(
          pk, (uint2v*)(obf + (size_t)n * 256 + sl * 32 + f * 4));
    } else {
      float v0 = acc0 * sc0 + sh0;
      float v1 = acc1 * sc1 + sh1;
      v0 = (v0 > 0.f) ? v0 : (__expf(v0) - 1.f);
      v1 = (v1 > 0.f) ? v1 : (__expf(v1) - 1.f);
      f2v v2;
      v2.x = v0; v2.y = v1;
      __builtin_nontemporal_store(
          v2, (f2v*)(of32 + (size_t)n * 128 + sl * 16 + f * 2));
    }
  }
}

// ---------------- layer-3 prep: h3 = o2 @ W3, als3/ald3 ---------------------

__global__ __launch_bounds__(256) void l3_prep_kernel(
    const float* __restrict__ o2, const float* __restrict__ W3,
    const float* __restrict__ a3s, const float* __restrict__ a3d,
    float4* __restrict__ h3p, float* __restrict__ ald3, int n_nodes) {
  __shared__ float w3s[384];
  __shared__ float sa3[6];
  for (int i = threadIdx.x; i < 384; i += 256) w3s[i] = W3[i];
  if (threadIdx.x < 3) {
    sa3[threadIdx.x] = a3s[threadIdx.x];
    sa3[3 + threadIdx.x] = a3d[threadIdx.x];
  }
  __syncthreads();
  int wid = threadIdx.x >> 6, lane = threadIdx.x & 63;
  int n = blockIdx.x * 4 + wid;
  if (n >= n_nodes) return;
  f2v v = *(const f2v*)(o2 + (size_t)n * 128 + lane * 2);  // phys cols lane*2,+1
  int hd = lane >> 4;
  int k0l = hd * 32 + (lane & 15);  // logical k of phys col lane*2
  int k1l = k0l + 16;               // logical k of phys col lane*2+1
  float p0 = v.x * w3s[k0l * 3 + 0] + v.y * w3s[k1l * 3 + 0];
  float p1 = v.x * w3s[k0l * 3 + 1] + v.y * w3s[k1l * 3 + 1];
  float p2 = v.x * w3s[k0l * 3 + 2] + v.y * w3s[k1l * 3 + 2];
#pragma unroll
  for (int off = 32; off >= 1; off >>= 1) {
    p0 += __shfl_xor(p0, off, 64);
    p1 += __shfl_xor(p1, off, 64);
    p2 += __shfl_xor(p2, off, 64);
  }
  if (lane == 0) {
    float als3 = p0 * sa3[0] + p1 * sa3[1] + p2 * sa3[2];
    float ad3 = p0 * sa3[3] + p1 * sa3[4] + p2 * sa3[5];
    h3p[n] = make_float4(p0, p1, p2, als3);
    ald3[n] = ad3;
  }
}

// ---------------- layer 3 aggregation + log_softmax -------------------------

__global__ __launch_bounds__(256) void l3_agg_kernel(const float4* __restrict__ h3p,
                                                     const float* __restrict__ ald3,
                                                     const int* __restrict__ row_start,
                                                     const int* __restrict__ csr_src,
                                                     const float* __restrict__ b3,
                                                     float* __restrict__ out, int n_nodes) {
  int wid = threadIdx.x >> 6, lane = threadIdx.x & 63;
  int n = __builtin_amdgcn_readfirstlane(blockIdx.x * 4 + wid);
  if (n >= n_nodes) return;
  float aldv = ald3[n];
  int row = __builtin_amdgcn_readfirstlane(row_start[n]);
  int end = __builtin_amdgcn_readfirstlane(row_start[n + 1]);
  const char* hp = (const char*)h3p;
  float a0 = 0.f, a1 = 0.f, a2 = 0.f, ss = 0.f;
  for (int i = row + lane; i < end; i += 64) {
    int s = csr_src[i];
    float4 hv = *(const float4*)(hp + ((unsigned)s * 16u));
    float e = hv.w + aldv;
    e = fmaxf(e, 0.2f * e);
    float ex = __expf(e);
    ss += ex;
    a0 += ex * hv.x;
    a1 += ex * hv.y;
    a2 += ex * hv.z;
  }
#pragma unroll
  for (int off = 32; off >= 1; off >>= 1) {
    a0 += __shfl_xor(a0, off, 64);
    a1 += __shfl_xor(a1, off, 64);
    a2 += __shfl_xor(a2, off, 64);
    ss += __shfl_xor(ss, off, 64);
  }
  if (lane == 0) {
    float inv = 1.f / (ss + 1e-16f);
    float o0 = a0 * inv + b3[0];
    float o1 = a1 * inv + b3[1];
    float o2 = a2 * inv + b3[2];
    float m = fmaxf(o0, fmaxf(o1, o2));
    float lse = m + logf(expf(o0 - m) + expf(o1 - m) + expf(o2 - m));
    out[n * 3 + 0] = o0 - lse;
    out[n * 3 + 1] = o1 - lse;
    out[n * 3 + 2] = o2 - lse;
  }
}

// ---------------------------------------------------------------------------

extern "C" void kernel_launch(void* const* d_in, const int* in_sizes, int n_in,
                              void* d_out, int out_size, void* d_ws, size_t ws_size,
                              hipStream_t stream) {
  const float* x   = (const float*)d_in[0];
  const int*   ei  = (const int*)d_in[1];
  const float* W1  = (const float*)d_in[2];
  const float* a1s = (const float*)d_in[3];
  const float* a1d = (const float*)d_in[4];
  const float* b1  = (const float*)d_in[5];
  const float* g1v = (const float*)d_in[6];
  const float* be1 = (const float*)d_in[7];
  const float* m1  = (const float*)d_in[8];
  const float* v1  = (const float*)d_in[9];
  const float* W2  = (const float*)d_in[10];
  const float* a2s = (const float*)d_in[11];
  const float* a2d = (const float*)d_in[12];
  const float* b2  = (const float*)d_in[13];
  const float* g2v = (const float*)d_in[14];
  const float* be2 = (const float*)d_in[15];
  const float* m2  = (const float*)d_in[16];
  const float* v2  = (const float*)d_in[17];
  const float* W3  = (const float*)d_in[18];
  const float* a3s = (const float*)d_in[19];
  const float* a3d = (const float*)d_in[20];
  const float* b3  = (const float*)d_in[21];
  float* out = (float*)d_out;

  const int N = in_sizes[0] / 128;  // 50000
  const int E = in_sizes[1] / 2;    // 850000
  const int* srcv = ei;
  const int* dstv = ei + E;

  // workspace carve-up (~73.5 MB), h2s LAST so alpha1 can alias + spill
  float* wsf  = (float*)d_ws;
  float* als1 = wsf;                   // N*4
  float* ald1 = als1 + (size_t)N * 4;
  float* als2 = ald1 + (size_t)N * 4;
  float* ald2 = als2 + (size_t)N * 4;
  float* h3p  = ald2 + (size_t)N * 4;  // N*4 (float4 rows)
  float* ald3 = h3p + (size_t)N * 4;   // N
  unsigned short* h1s   = (unsigned short*)(ald3 + N);  // N*256 (8 subtables N*32)
  unsigned short* o1_bf = h1s + (size_t)N * 256;        // N*256 row-major phys
  unsigned short* W1t   = o1_bf + (size_t)N * 256;      // 256*128
  unsigned short* W2t   = W1t + 256 * 128;              // 128*256
  int* deg       = (int*)(W2t + 128 * 256);  // N
  int* row_start = deg + N;                  // N+1
  int* cursor    = row_start + (N + 1);      // N+1
  int* csr_src   = cursor + (N + 1);         // E
  int* bsum      = csr_src + E;              // 1024
  float* bnsc1 = (float*)(bsum + 1024);      // 256
  float* bnsh1 = bnsc1 + 256;                // 256
  float* bnsc2 = bnsh1 + 256;                // 128
  float* bnsh2 = bnsc2 + 128;                // 128
  int* dh      = (int*)(bnsh2 + 128);        // 64
  int* dcur    = dh + 64;                    // 64
  int* nodeord = dcur + 64;                  // N + 64
  unsigned short* h2s = (unsigned short*)(nodeord + N + 64);  // N*128 LAST
  // aliases (lifetimes disjoint):
  float* alpha1 = (float*)h2s;    // 4*E f32; dead before gemm2 writes h2s
  float* alpha2 = (float*)o1_bf;  // 4*E f32; o1_bf dead after gemm2 reads it
  float* o2f    = (float*)h1s;    // N*128 f32; h1s dead after agg1

  const int eb = (E + 255) / 256;
  const int nb = (N + 1023) / 1024;
  const int nodes4 = (N + 3) / 4;
  const int mblocks = (N + 63) / 64;
  const int aggblocks = ((N + 31) / 32) * 8;  // 32 nodes/block x 8 slices

  // weight conversions + BN fold
  conv_w1t_kernel<<<128, 256, 0, stream>>>(W1, W1t);
  conv_w2t_kernel<<<128, 256, 0, stream>>>(W2, W2t);
  bn_prep_kernel<<<1, 512, 0, stream>>>(b1, g1v, be1, m1, v1, b2, g2v, be2, m2, v2,
                                        bnsc1, bnsh1, bnsc2, bnsh2);

  // CSR build (shared by all 3 layers)
  hipMemsetAsync(deg, 0, (size_t)N * sizeof(int), stream);
  hipMemsetAsync(dh, 0, 64 * sizeof(int), stream);
  hist_kernel<<<eb, 256, 0, stream>>>(dstv, E, deg);
  block_sums_kernel<<<nb, 256, 0, stream>>>(deg, N, bsum);
  tiny_scan_kernel<<<1, 64, 0, stream>>>(bsum, nb);
  scan_write_kernel<<<nb, 256, 0, stream>>>(deg, N, bsum, row_start, cursor);
  scatter_kernel<<<eb, 256, 0, stream>>>(srcv, dstv, E, cursor, csr_src);
  // degree sort (shared by both aggs)
  dhist_kernel<<<nb * 4, 256, 0, stream>>>(deg, N, dh);
  dscan_kernel<<<1, 64, 0, stream>>>(dh, dcur, nodeord, N);
  dscatter_kernel<<<nb * 4, 256, 0, stream>>>(deg, N, dcur, nodeord);

  // layer 1
  gemm_mfma<128, 256, true><<<mblocks, 256, 0, stream>>>(x, W1t, a1s, a1d, h1s, als1,
                                                         ald1, N);
  alpha_kernel<<<nodes4, 256, 0, stream>>>(als1, ald1, row_start, csr_src, alpha1, E, N);
  gat_agg_slice<256><<<aggblocks, 256, 0, stream>>>(
      h1s, alpha1, row_start, csr_src, nodeord, bnsc1, bnsh1, o1_bf, nullptr, E, N);
  // layer 2
  gemm_mfma<256, 128, false><<<mblocks, 256, 0, stream>>>(o1_bf, W2t, a2s, a2d, h2s, als2,
                                                          ald2, N);
  alpha_kernel<<<nodes4, 256, 0, stream>>>(als2, ald2, row_start, csr_src, alpha2, E, N);
  gat_agg_slice<128><<<aggblocks, 256, 0, stream>>>(
      h2s, alpha2, row_start, csr_src, nodeord, bnsc2, bnsh2, nullptr, o2f, E, N);
  // layer 3 prep + aggregation + log_softmax
  l3_prep_kernel<<<nodes4, 256, 0, stream>>>(o2f, W3, a3s, a3d, (float4*)h3p, ald3, N);
  l3_agg_kernel<<<nodes4, 256, 0, stream>>>((const float4*)h3p, ald3, row_start, csr_src,
                                            b3, out, N);
}

// Round 8
// 471.768 us; speedup vs baseline: 1.5775x; 1.5775x over previous
//
#include <hip/hip_runtime.h>

// ---------------------------------------------------------------------------
// DoshaGAT: 3-layer GAT. R12 (= R11 with contention-free degree sort):
//  - R11's dhist/dscatter did 50k global atomics into 64 addresses ->
//    ~139us each of pure atomic-retry serialization. Replaced with two-level
//    counting sort: per-block LDS histogram -> bh[nb][64]; single-block scan
//    rewrites bh to global start offsets; per-block LDS-rank scatter. Zero
//    global atomics.
//  - Everything else verbatim from R11 (sorted sliced agg unroll 4,
//    single-pass alpha, slice-major h, XCD %8, folded BN, GEMM, l3).
// ---------------------------------------------------------------------------

#define WSZ 64

typedef short short8 __attribute__((ext_vector_type(8)));
typedef short short4v __attribute__((ext_vector_type(4)));
typedef float float4v __attribute__((ext_vector_type(4)));
typedef float f2v __attribute__((ext_vector_type(2)));
typedef unsigned uint2v __attribute__((ext_vector_type(2)));

__device__ inline unsigned short f2bf(float f) {  // RNE f32->bf16
  unsigned u = __float_as_uint(f);
  u += 0x7FFFu + ((u >> 16) & 1u);
  return (unsigned short)(u >> 16);
}
__device__ inline float bf2f(unsigned short u) {
  return __uint_as_float(((unsigned)u) << 16);
}

// ---------------- CSR build ----------------

__global__ __launch_bounds__(256) void hist_kernel(const int* __restrict__ dst, int E,
                                                   int* __restrict__ deg) {
  int e = blockIdx.x * 256 + threadIdx.x;
  if (e < E) atomicAdd(&deg[dst[e]], 1);
}

__global__ __launch_bounds__(256) void block_sums_kernel(const int* __restrict__ deg, int n,
                                                         int* __restrict__ bsum) {
  __shared__ int sh[256];
  int t = threadIdx.x;
  int base = blockIdx.x * 1024 + t * 4;
  int v = 0;
#pragma unroll
  for (int j = 0; j < 4; ++j) {
    int idx = base + j;
    if (idx < n) v += deg[idx];
  }
  sh[t] = v;
  __syncthreads();
  for (int off = 128; off >= 1; off >>= 1) {
    if (t < off) sh[t] += sh[t + off];
    __syncthreads();
  }
  if (t == 0) bsum[blockIdx.x] = sh[0];
}

__global__ void tiny_scan_kernel(int* bsum, int nb) {
  if (threadIdx.x == 0 && blockIdx.x == 0) {
    int run = 0;
    for (int i = 0; i < nb; ++i) {
      int v = bsum[i];
      bsum[i] = run;
      run += v;
    }
  }
}

__global__ __launch_bounds__(256) void scan_write_kernel(const int* __restrict__ deg, int n,
                                                         const int* __restrict__ bbase,
                                                         int* __restrict__ row_start,
                                                         int* __restrict__ cursor) {
  __shared__ int sh[256];
  int t = threadIdx.x;
  int base = blockIdx.x * 1024 + t * 4;
  int v[4];
  int s = 0;
#pragma unroll
  for (int j = 0; j < 4; ++j) {
    int idx = base + j;
    v[j] = (idx < n) ? deg[idx] : 0;
    s += v[j];
  }
  sh[t] = s;
  __syncthreads();
  for (int off = 1; off < 256; off <<= 1) {
    int x = (t >= off) ? sh[t - off] : 0;
    __syncthreads();
    sh[t] += x;
    __syncthreads();
  }
  int excl = sh[t] - s + bbase[blockIdx.x];
#pragma unroll
  for (int j = 0; j < 4; ++j) {
    int idx = base + j;
    if (idx < n) {
      row_start[idx] = excl;
      cursor[idx] = excl;
    }
    excl += v[j];
  }
  if (blockIdx.x == gridDim.x - 1 && t == 255) row_start[n] = excl;  // == E
}

__global__ __launch_bounds__(256) void scatter_kernel(const int* __restrict__ src,
                                                      const int* __restrict__ dst, int E,
                                                      int* __restrict__ cursor,
                                                      int* __restrict__ csr_src) {
  int e = blockIdx.x * 256 + threadIdx.x;
  if (e < E) {
    int d = dst[e];
    int p = atomicAdd(&cursor[d], 1);
    csr_src[p] = src[e];
  }
}

// ---------------- degree sort: two-level counting sort (no global atomics) --

__global__ __launch_bounds__(256) void dhist2_kernel(const int* __restrict__ deg, int N,
                                                     int* __restrict__ bh) {
  __shared__ int h[64];
  int t = threadIdx.x;
  if (t < 64) h[t] = 0;
  __syncthreads();
  int base = blockIdx.x * 1024 + t * 4;
#pragma unroll
  for (int j = 0; j < 4; ++j) {
    int n = base + j;
    if (n < N) atomicAdd(&h[min(deg[n], 63)], 1);
  }
  __syncthreads();
  if (t < 64) bh[blockIdx.x * 64 + t] = h[t];
}

__global__ void dscan2_kernel(int* __restrict__ bh, int nblk,
                              int* __restrict__ nodeord, int N) {
  __shared__ int tot[64];
  __shared__ int basebuf[64];
  int b = threadIdx.x;  // bucket
  int sum = 0;
  for (int k = 0; k < nblk; ++k) sum += bh[k * 64 + b];
  tot[b] = sum;
  __syncthreads();
  if (b == 0) {
    int run = 0;
    for (int i = 0; i < 64; ++i) {
      basebuf[i] = run;
      run += tot[i];
    }
  }
  __syncthreads();
  int off = basebuf[b];
  for (int k = 0; k < nblk; ++k) {
    int c = bh[k * 64 + b];
    bh[k * 64 + b] = off;
    off += c;
  }
  nodeord[N + b] = 0;  // pad
}

__global__ __launch_bounds__(256) void dscatter2_kernel(const int* __restrict__ deg, int N,
                                                        const int* __restrict__ bh,
                                                        int* __restrict__ nodeord) {
  __shared__ int cnt[64];
  __shared__ int start[64];
  int t = threadIdx.x;
  if (t < 64) {
    cnt[t] = 0;
    start[t] = bh[blockIdx.x * 64 + t];
  }
  __syncthreads();
  int base = blockIdx.x * 1024 + t * 4;
#pragma unroll
  for (int j = 0; j < 4; ++j) {
    int n = base + j;
    if (n < N) {
      int bk = min(deg[n], 63);
      int r = atomicAdd(&cnt[bk], 1);
      nodeord[start[bk] + r] = n;
    }
  }
}

// ---------------- weight conversion + BN fold ----------------

// W1 [128][256] -> W1t [256][128] bf16
__global__ __launch_bounds__(256) void conv_w1t_kernel(const float* __restrict__ W1,
                                                       unsigned short* __restrict__ W1t) {
  int idx = blockIdx.x * 256 + threadIdx.x;  // 32768
  int n = idx >> 7, k = idx & 127;
  W1t[idx] = f2bf(W1[k * 256 + n]);
}

// W2 [256][128] -> W2t [128][256] bf16, K rows permuted to layer-1 phys layout
__global__ __launch_bounds__(256) void conv_w2t_kernel(const float* __restrict__ W2,
                                                       unsigned short* __restrict__ W2t) {
  int idx = blockIdx.x * 256 + threadIdx.x;  // 32768
  int n = idx >> 8, p = idx & 255;
  int kl = (p & ~63) | ((p & 3) << 4) | ((p >> 2) & 15);
  W2t[idx] = f2bf(W2[kl * 128 + n]);
}

// fold bias+BN into per-logical-col scale/shift: o*sc + sh
__global__ __launch_bounds__(512) void bn_prep_kernel(
    const float* __restrict__ b1, const float* __restrict__ g1,
    const float* __restrict__ be1, const float* __restrict__ m1,
    const float* __restrict__ v1, const float* __restrict__ b2,
    const float* __restrict__ g2, const float* __restrict__ be2,
    const float* __restrict__ m2, const float* __restrict__ v2,
    float* __restrict__ sc1, float* __restrict__ sh1,
    float* __restrict__ sc2, float* __restrict__ sh2) {
  int t = threadIdx.x;
  if (t < 256) {
    float s = g1[t] * rsqrtf(v1[t] + 1e-5f);
    sc1[t] = s;
    sh1[t] = (b1[t] - m1[t]) * s + be1[t];
  } else if (t < 384) {
    int i = t - 256;
    float s = g2[i] * rsqrtf(v2[i] + 1e-5f);
    sc2[i] = s;
    sh2[i] = (b2[i] - m2[i]) * s + be2[i];
  }
}

// ---------------- bf16 MFMA GEMM + fused attn-coeff epilogue ----------------
// C[M,BN] = A[M,K] @ B[K,BN]. 64-row blocks, 256 threads, 4 waves (wave=head).
// AF32: A is f32, converted to bf16 during LDS staging.
// hout is written SLICE-MAJOR: 8 subtables of [M][BN/8] bf16.

template <int K, int BN, bool AF32>
__global__ __launch_bounds__(256) void gemm_mfma(
    const void* __restrict__ Ap,            // [M][K] bf16 or f32
    const unsigned short* __restrict__ Bt,  // [BN][K] bf16 (pre-transposed)
    const float* __restrict__ a_s, const float* __restrict__ a_d,  // [BN] logical
    unsigned short* __restrict__ hout,      // slice-major output
    float* __restrict__ als, float* __restrict__ ald,  // [M][4]
    int M) {
  constexpr int CF = BN / 64;  // col frags per wave
  constexpr int SF = BN / 8;   // feats per slice (32 or 16)
  constexpr int PAD = 36;
  __shared__ unsigned short As[64][PAD];
  __shared__ unsigned short Bs[BN][PAD];
  const int t = threadIdx.x;
  const int w = t >> 6;
  const int lane = t & 63;
  const int c16 = lane & 15;
  const int q = lane >> 4;
  const int bm = blockIdx.x * 64;
  const int arow = t >> 2;      // 0..63
  const int akc = (t & 3) * 8;  // 0,8,16,24

  float4v acc[4][CF];
#pragma unroll
  for (int rf = 0; rf < 4; ++rf)
#pragma unroll
    for (int cf = 0; cf < CF; ++cf) acc[rf][cf] = float4v{0.f, 0.f, 0.f, 0.f};

  for (int k0 = 0; k0 < K; k0 += 32) {
    {  // stage A tile 64x32 (8 elems/thread)
      int gr = bm + arow;
      if constexpr (AF32) {
        const float* Af = (const float*)Ap + (size_t)gr * K + k0 + akc;
        float4 v0 = make_float4(0.f, 0.f, 0.f, 0.f), v1 = v0;
        if (gr < M) {
          v0 = *(const float4*)Af;
          v1 = *(const float4*)(Af + 4);
        }
        ushort4 u0, u1;
        u0.x = f2bf(v0.x); u0.y = f2bf(v0.y); u0.z = f2bf(v0.z); u0.w = f2bf(v0.w);
        u1.x = f2bf(v1.x); u1.y = f2bf(v1.y); u1.z = f2bf(v1.z); u1.w = f2bf(v1.w);
        *(ushort4*)&As[arow][akc] = u0;
        *(ushort4*)&As[arow][akc + 4] = u1;
      } else {
        uint4 v = make_uint4(0u, 0u, 0u, 0u);
        if (gr < M) v = *(const uint4*)((const unsigned short*)Ap + (size_t)gr * K + k0 + akc);
        *(uint2*)&As[arow][akc] = make_uint2(v.x, v.y);
        *(uint2*)&As[arow][akc + 4] = make_uint2(v.z, v.w);
      }
    }
#pragma unroll
    for (int h = 0; h < BN / 64; ++h) {  // stage B tile BNx32
      int n = (t >> 2) + h * 64;
      uint4 v = *(const uint4*)(Bt + (size_t)n * K + k0 + akc);
      *(uint2*)&Bs[n][akc] = make_uint2(v.x, v.y);
      *(uint2*)&Bs[n][akc + 4] = make_uint2(v.z, v.w);
    }
    __syncthreads();
    short8 af[4], bfr[CF];
#pragma unroll
    for (int rf = 0; rf < 4; ++rf) {
      short4v lo = *(short4v*)&As[rf * 16 + c16][q * 8];
      short4v hi = *(short4v*)&As[rf * 16 + c16][q * 8 + 4];
      af[rf] = __builtin_shufflevector(lo, hi, 0, 1, 2, 3, 4, 5, 6, 7);
    }
#pragma unroll
    for (int cf = 0; cf < CF; ++cf) {
      int n = w * (CF * 16) + cf * 16 + c16;
      short4v lo = *(short4v*)&Bs[n][q * 8];
      short4v hi = *(short4v*)&Bs[n][q * 8 + 4];
      bfr[cf] = __builtin_shufflevector(lo, hi, 0, 1, 2, 3, 4, 5, 6, 7);
    }
#pragma unroll
    for (int rf = 0; rf < 4; ++rf)
#pragma unroll
      for (int cf = 0; cf < CF; ++cf)
        acc[rf][cf] =
            __builtin_amdgcn_mfma_f32_16x16x32_bf16(af[rf], bfr[cf], acc[rf][cf], 0, 0, 0);
    __syncthreads();
  }

  float sasv[CF], sadv[CF];
#pragma unroll
  for (int cf = 0; cf < CF; ++cf) {
    int L = w * (CF * 16) + cf * 16 + c16;
    sasv[cf] = a_s[L];
    sadv[cf] = a_d[L];
  }
  // slice-major store base: subtable = w*2 + (c16>>3)
  const size_t sub = (size_t)(w * 2 + (c16 >> 3)) * (size_t)M * SF;
#pragma unroll
  for (int rf = 0; rf < 4; ++rf) {
#pragma unroll
    for (int r = 0; r < 4; ++r) {
      int n = bm + rf * 16 + q * 4 + r;
      float ps = 0.f, pd = 0.f;
      unsigned short us[CF];
#pragma unroll
      for (int cf = 0; cf < CF; ++cf) {
        float v = acc[rf][cf][r];
        us[cf] = f2bf(v);
        ps += v * sasv[cf];
        pd += v * sadv[cf];
      }
#pragma unroll
      for (int off = 1; off <= 8; off <<= 1) {
        ps += __shfl_xor(ps, off, 16);
        pd += __shfl_xor(pd, off, 16);
      }
      if (n < M) {
        if constexpr (CF == 4) {
          ushort4 u;
          u.x = us[0]; u.y = us[1]; u.z = us[2]; u.w = us[3];
          *(ushort4*)(hout + sub + (size_t)n * 32 + (c16 & 7) * 4) = u;
        } else {
          ushort2 u;
          u.x = us[0]; u.y = us[1];
          *(ushort2*)(hout + sub + (size_t)n * 16 + (c16 & 7) * 2) = u;
        }
        if (c16 == 0) {
          als[(size_t)n * 4 + w] = ps;
          ald[(size_t)n * 4 + w] = pd;
        }
      }
    }
  }
}

// ---------------- alpha precompute (single-pass, reg-stashed exp) -----------

__global__ __launch_bounds__(256) void alpha_kernel(
    const float* __restrict__ als, const float* __restrict__ ald,
    const int* __restrict__ row_start, const int* __restrict__ csr_src,
    float* __restrict__ alpha, int E, int n_nodes) {
  int wid = threadIdx.x >> 6, lane = threadIdx.x & 63;
  int n = __builtin_amdgcn_readfirstlane(blockIdx.x * 4 + wid);
  if (n >= n_nodes) return;
  int head = lane & 3;
  int eg = lane >> 2;  // 16 edge slots
  float aldv = ald[(size_t)n * 4 + head];
  int row = __builtin_amdgcn_readfirstlane(row_start[n]);
  int end = __builtin_amdgcn_readfirstlane(row_start[n + 1]);
  float ex0 = 0.f, ex1 = 0.f, ex2 = 0.f, ex3 = 0.f;

#define ABLK(exK, base)                                             \
  {                                                                 \
    int e = (base) + eg;                                            \
    int ec = (e < end) ? e : (end - 1);                             \
    int s = csr_src[ec];                                            \
    float xv = als[(size_t)(unsigned)s * 4 + head] + aldv;          \
    xv = fmaxf(xv, 0.2f * xv);                                      \
    exK = (e < end) ? __expf(xv) : 0.f;                             \
  }

  ABLK(ex0, row)
  if (end > row + 16) ABLK(ex1, row + 16)
  if (end > row + 32) ABLK(ex2, row + 32)
  if (end > row + 48) ABLK(ex3, row + 48)
  float ssum = (ex0 + ex1) + (ex2 + ex3);
  for (int i = row + 64; i < end; i += 16) {  // residual (deg > 64, rare)
    int e = i + eg;
    int ec = (e < end) ? e : (end - 1);
    int s = csr_src[ec];
    float xv = als[(size_t)(unsigned)s * 4 + head] + aldv;
    xv = fmaxf(xv, 0.2f * xv);
    ssum += (e < end) ? __expf(xv) : 0.f;
  }
  ssum += __shfl_xor(ssum, 4, 64);
  ssum += __shfl_xor(ssum, 8, 64);
  ssum += __shfl_xor(ssum, 16, 64);
  ssum += __shfl_xor(ssum, 32, 64);
  float inv = 1.f / (ssum + 1e-16f);
  float* apl = alpha + (size_t)head * (unsigned)E;
  if (row + eg < end) apl[row + eg] = ex0 * inv;
  if (end > row + 16 && row + 16 + eg < end) apl[row + 16 + eg] = ex1 * inv;
  if (end > row + 32 && row + 32 + eg < end) apl[row + 32 + eg] = ex2 * inv;
  if (end > row + 48 && row + 48 + eg < end) apl[row + 48 + eg] = ex3 * inv;
  for (int i = row + 64; i < end; i += 16) {  // residual pass B
    int e = i + eg;
    if (e < end) {
      int s = csr_src[e];
      float xv = als[(size_t)(unsigned)s * 4 + head] + aldv;
      xv = fmaxf(xv, 0.2f * xv);
      apl[e] = __expf(xv) * inv;
    }
  }
#undef ABLK
}

// ---------------- XCD-sliced GAT aggregation (8 sorted nodes/wave) ----------

template <int D>
__global__ __launch_bounds__(256) void gat_agg_slice(
    const unsigned short* __restrict__ h_sl,  // 8 slice-major subtables
    const float* __restrict__ alpha,          // [4][E]
    const int* __restrict__ row_start, const int* __restrict__ csr_src,
    const int* __restrict__ nodeord,          // degree-sorted, padded
    const float* __restrict__ bnsc, const float* __restrict__ bnsh,  // [D] logical
    unsigned short* __restrict__ obf,  // D==256 out (bf16 phys rows)
    float* __restrict__ of32,          // D==128 out (f32 phys rows)
    int E, int n_nodes) {
  constexpr int SFEAT = D / 8;   // 32 | 16
  constexpr int KF = SFEAT / 8;  // feats per lane: 4 | 2
  const int sl = blockIdx.x & 7;
  const int g = blockIdx.x >> 3;
  const int wid = threadIdx.x >> 6, lane = threadIdx.x & 63;
  const int f = lane & 7;    // feat slot
  const int ng = lane >> 3;  // node sub-slot 0..7
  const int head = sl >> 1;
  const char* hb = (const char*)(h_sl + (size_t)sl * (unsigned)n_nodes * SFEAT);
  const char* cb = (const char*)csr_src;
  const char* apb = (const char*)(alpha + (size_t)head * (unsigned)E);
  const unsigned uoff = (unsigned)(f * KF * 2);  // byte off in slice row

  // folded BN constants for this lane's logical cols (independent of node)
  const int lb = (D == 256 ? head * 64 : head * 32) + (sl & 1) * 8 + f;
  float sc0 = bnsc[lb], sh0 = bnsh[lb];
  float sc1 = bnsc[lb + 16], sh1 = bnsh[lb + 16];
  float sc2 = 0.f, sh2 = 0.f, sc3 = 0.f, sh3 = 0.f;
  if constexpr (D == 256) {
    sc2 = bnsc[lb + 32]; sh2 = bnsh[lb + 32];
    sc3 = bnsc[lb + 48]; sh3 = bnsh[lb + 48];
  }

  int slot = g * 32 + wid * 8 + ng;
  bool valid = slot < n_nodes;
  int n = nodeord[slot];  // padded past n_nodes with 0
  int row = row_start[n];
  int deg = row_start[n + 1] - row;
  if (!valid) deg = 0;
  // wave-max degree (ng lives in lane bits 3..5)
  int mx = deg;
#pragma unroll
  for (int off = 8; off <= 32; off <<= 1) mx = max(mx, __shfl_xor(mx, off, 64));
  mx = __builtin_amdgcn_readfirstlane(mx);

  float acc0 = 0.f, acc1 = 0.f, acc2 = 0.f, acc3 = 0.f;
#pragma unroll 4
  for (int j = 0; j < mx; ++j) {
    bool act = j < deg;
    unsigned idx = (unsigned)(row + (act ? j : 0));
    int s = *(const int*)(cb + idx * 4u);
    float a = *(const float*)(apb + idx * 4u);
    a = act ? a : 0.f;
    if constexpr (D == 256) {
      uint2v u = *(const uint2v*)(hb + ((unsigned)s * 64u + uoff));
      acc0 += a * __uint_as_float(u.x << 16);
      acc1 += a * __uint_as_float(u.x & 0xffff0000u);
      acc2 += a * __uint_as_float(u.y << 16);
      acc3 += a * __uint_as_float(u.y & 0xffff0000u);
    } else {
      unsigned u = *(const unsigned*)(hb + ((unsigned)s * 32u + uoff));
      acc0 += a * __uint_as_float(u << 16);
      acc1 += a * __uint_as_float(u & 0xffff0000u);
    }
  }

  if (valid) {
    if constexpr (D == 256) {
      float v0 = acc0 * sc0 + sh0;
      float v1 = acc1 * sc1 + sh1;
      float v2 = acc2 * sc2 + sh2;
      float v3 = acc3 * sc3 + sh3;
      v0 = (v0 > 0.f) ? v0 : (__expf(v0) - 1.f);
      v1 = (v1 > 0.f) ? v1 : (__expf(v1) - 1.f);
      v2 = (v2 > 0.f) ? v2 : (__expf(v2) - 1.f);
      v3 = (v3 > 0.f) ? v3 : (__expf(v3) - 1.f);
      uint2v pk;
      pk.x = (unsigned)f2bf(v0) | ((unsigned)f2bf(v1) << 16);
      pk.y = (unsigned)f2bf(v2) | ((unsigned)f2bf(v3) << 16);
      __builtin_nontemporal_store(
          pk, (uint2v*)(obf + (size_t)n * 256 + sl * 32 + f * 4));
    } else {
      float v0 = acc0 * sc0 + sh0;
      float v1 = acc1 * sc1 + sh1;
      v0 = (v0 > 0.f) ? v0 : (__expf(v0) - 1.f);
      v1 = (v1 > 0.f) ? v1 : (__expf(v1) - 1.f);
      f2v v2;
      v2.x = v0; v2.y = v1;
      __builtin_nontemporal_store(
          v2, (f2v*)(of32 + (size_t)n * 128 + sl * 16 + f * 2));
    }
  }
}

// ---------------- layer-3 prep: h3 = o2 @ W3, als3/ald3 ---------------------

__global__ __launch_bounds__(256) void l3_prep_kernel(
    const float* __restrict__ o2, const float* __restrict__ W3,
    const float* __restrict__ a3s, const float* __restrict__ a3d,
    float4* __restrict__ h3p, float* __restrict__ ald3, int n_nodes) {
  __shared__ float w3s[384];
  __shared__ float sa3[6];
  for (int i = threadIdx.x; i < 384; i += 256) w3s[i] = W3[i];
  if (threadIdx.x < 3) {
    sa3[threadIdx.x] = a3s[threadIdx.x];
    sa3[3 + threadIdx.x] = a3d[threadIdx.x];
  }
  __syncthreads();
  int wid = threadIdx.x >> 6, lane = threadIdx.x & 63;
  int n = blockIdx.x * 4 + wid;
  if (n >= n_nodes) return;
  f2v v = *(const f2v*)(o2 + (size_t)n * 128 + lane * 2);  // phys cols lane*2,+1
  int hd = lane >> 4;
  int k0l = hd * 32 + (lane & 15);  // logical k of phys col lane*2
  int k1l = k0l + 16;               // logical k of phys col lane*2+1
  float p0 = v.x * w3s[k0l * 3 + 0] + v.y * w3s[k1l * 3 + 0];
  float p1 = v.x * w3s[k0l * 3 + 1] + v.y * w3s[k1l * 3 + 1];
  float p2 = v.x * w3s[k0l * 3 + 2] + v.y * w3s[k1l * 3 + 2];
#pragma unroll
  for (int off = 32; off >= 1; off >>= 1) {
    p0 += __shfl_xor(p0, off, 64);
    p1 += __shfl_xor(p1, off, 64);
    p2 += __shfl_xor(p2, off, 64);
  }
  if (lane == 0) {
    float als3 = p0 * sa3[0] + p1 * sa3[1] + p2 * sa3[2];
    float ad3 = p0 * sa3[3] + p1 * sa3[4] + p2 * sa3[5];
    h3p[n] = make_float4(p0, p1, p2, als3);
    ald3[n] = ad3;
  }
}

// ---------------- layer 3 aggregation + log_softmax -------------------------

__global__ __launch_bounds__(256) void l3_agg_kernel(const float4* __restrict__ h3p,
                                                     const float* __restrict__ ald3,
                                                     const int* __restrict__ row_start,
                                                     const int* __restrict__ csr_src,
                                                     const float* __restrict__ b3,
                                                     float* __restrict__ out, int n_nodes) {
  int wid = threadIdx.x >> 6, lane = threadIdx.x & 63;
  int n = __builtin_amdgcn_readfirstlane(blockIdx.x * 4 + wid);
  if (n >= n_nodes) return;
  float aldv = ald3[n];
  int row = __builtin_amdgcn_readfirstlane(row_start[n]);
  int end = __builtin_amdgcn_readfirstlane(row_start[n + 1]);
  const char* hp = (const char*)h3p;
  float a0 = 0.f, a1 = 0.f, a2 = 0.f, ss = 0.f;
  for (int i = row + lane; i < end; i += 64) {
    int s = csr_src[i];
    float4 hv = *(const float4*)(hp + ((unsigned)s * 16u));
    float e = hv.w + aldv;
    e = fmaxf(e, 0.2f * e);
    float ex = __expf(e);
    ss += ex;
    a0 += ex * hv.x;
    a1 += ex * hv.y;
    a2 += ex * hv.z;
  }
#pragma unroll
  for (int off = 32; off >= 1; off >>= 1) {
    a0 += __shfl_xor(a0, off, 64);
    a1 += __shfl_xor(a1, off, 64);
    a2 += __shfl_xor(a2, off, 64);
    ss += __shfl_xor(ss, off, 64);
  }
  if (lane == 0) {
    float inv = 1.f / (ss + 1e-16f);
    float o0 = a0 * inv + b3[0];
    float o1 = a1 * inv + b3[1];
    float o2 = a2 * inv + b3[2];
    float m = fmaxf(o0, fmaxf(o1, o2));
    float lse = m + logf(expf(o0 - m) + expf(o1 - m) + expf(o2 - m));
    out[n * 3 + 0] = o0 - lse;
    out[n * 3 + 1] = o1 - lse;
    out[n * 3 + 2] = o2 - lse;
  }
}

// ---------------------------------------------------------------------------

extern "C" void kernel_launch(void* const* d_in, const int* in_sizes, int n_in,
                              void* d_out, int out_size, void* d_ws, size_t ws_size,
                              hipStream_t stream) {
  const float* x   = (const float*)d_in[0];
  const int*   ei  = (const int*)d_in[1];
  const float* W1  = (const float*)d_in[2];
  const float* a1s = (const float*)d_in[3];
  const float* a1d = (const float*)d_in[4];
  const float* b1  = (const float*)d_in[5];
  const float* g1v = (const float*)d_in[6];
  const float* be1 = (const float*)d_in[7];
  const float* m1  = (const float*)d_in[8];
  const float* v1  = (const float*)d_in[9];
  const float* W2  = (const float*)d_in[10];
  const float* a2s = (const float*)d_in[11];
  const float* a2d = (const float*)d_in[12];
  const float* b2  = (const float*)d_in[13];
  const float* g2v = (const float*)d_in[14];
  const float* be2 = (const float*)d_in[15];
  const float* m2  = (const float*)d_in[16];
  const float* v2  = (const float*)d_in[17];
  const float* W3  = (const float*)d_in[18];
  const float* a3s = (const float*)d_in[19];
  const float* a3d = (const float*)d_in[20];
  const float* b3  = (const float*)d_in[21];
  float* out = (float*)d_out;

  const int N = in_sizes[0] / 128;  // 50000
  const int E = in_sizes[1] / 2;    // 850000
  const int* srcv = ei;
  const int* dstv = ei + E;

  const int eb = (E + 255) / 256;
  const int nb = (N + 1023) / 1024;
  const int nodes4 = (N + 3) / 4;
  const int mblocks = (N + 63) / 64;
  const int aggblocks = ((N + 31) / 32) * 8;  // 32 nodes/block x 8 slices

  // workspace carve-up (~73.5 MB), h2s LAST so alpha1 can alias + spill
  float* wsf  = (float*)d_ws;
  float* als1 = wsf;                   // N*4
  float* ald1 = als1 + (size_t)N * 4;
  float* als2 = ald1 + (size_t)N * 4;
  float* ald2 = als2 + (size_t)N * 4;
  float* h3p  = ald2 + (size_t)N * 4;  // N*4 (float4 rows)
  float* ald3 = h3p + (size_t)N * 4;   // N
  unsigned short* h1s   = (unsigned short*)(ald3 + N);  // N*256 (8 subtables N*32)
  unsigned short* o1_bf = h1s + (size_t)N * 256;        // N*256 row-major phys
  unsigned short* W1t   = o1_bf + (size_t)N * 256;      // 256*128
  unsigned short* W2t   = W1t + 256 * 128;              // 128*256
  int* deg       = (int*)(W2t + 128 * 256);  // N
  int* row_start = deg + N;                  // N+1
  int* cursor    = row_start + (N + 1);      // N+1
  int* csr_src   = cursor + (N + 1);         // E
  int* bsum      = csr_src + E;              // 1024
  float* bnsc1 = (float*)(bsum + 1024);      // 256
  float* bnsh1 = bnsc1 + 256;                // 256
  float* bnsc2 = bnsh1 + 256;                // 128
  float* bnsh2 = bnsc2 + 128;                // 128
  int* bh      = (int*)(bnsh2 + 128);        // nb*64 block-bucket table
  int* nodeord = bh + (size_t)nb * 64;       // N + 64
  unsigned short* h2s = (unsigned short*)(nodeord + N + 64);  // N*128 LAST
  // aliases (lifetimes disjoint):
  float* alpha1 = (float*)h2s;    // 4*E f32; dead before gemm2 writes h2s
  float* alpha2 = (float*)o1_bf;  // 4*E f32; o1_bf dead after gemm2 reads it
  float* o2f    = (float*)h1s;    // N*128 f32; h1s dead after agg1

  // weight conversions + BN fold
  conv_w1t_kernel<<<128, 256, 0, stream>>>(W1, W1t);
  conv_w2t_kernel<<<128, 256, 0, stream>>>(W2, W2t);
  bn_prep_kernel<<<1, 512, 0, stream>>>(b1, g1v, be1, m1, v1, b2, g2v, be2, m2, v2,
                                        bnsc1, bnsh1, bnsc2, bnsh2);

  // CSR build (shared by all 3 layers)
  hipMemsetAsync(deg, 0, (size_t)N * sizeof(int), stream);
  hist_kernel<<<eb, 256, 0, stream>>>(dstv, E, deg);
  block_sums_kernel<<<nb, 256, 0, stream>>>(deg, N, bsum);
  tiny_scan_kernel<<<1, 64, 0, stream>>>(bsum, nb);
  scan_write_kernel<<<nb, 256, 0, stream>>>(deg, N, bsum, row_start, cursor);
  scatter_kernel<<<eb, 256, 0, stream>>>(srcv, dstv, E, cursor, csr_src);
  // degree sort, contention-free (shared by both aggs)
  dhist2_kernel<<<nb, 256, 0, stream>>>(deg, N, bh);
  dscan2_kernel<<<1, 64, 0, stream>>>(bh, nb, nodeord, N);
  dscatter2_kernel<<<nb, 256, 0, stream>>>(deg, N, bh, nodeord);

  // layer 1
  gemm_mfma<128, 256, true><<<mblocks, 256, 0, stream>>>(x, W1t, a1s, a1d, h1s, als1,
                                                         ald1, N);
  alpha_kernel<<<nodes4, 256, 0, stream>>>(als1, ald1, row_start, csr_src, alpha1, E, N);
  gat_agg_slice<256><<<aggblocks, 256, 0, stream>>>(
      h1s, alpha1, row_start, csr_src, nodeord, bnsc1, bnsh1, o1_bf, nullptr, E, N);
  // layer 2
  gemm_mfma<256, 128, false><<<mblocks, 256, 0, stream>>>(o1_bf, W2t, a2s, a2d, h2s, als2,
                                                          ald2, N);
  alpha_kernel<<<nodes4, 256, 0, stream>>>(als2, ald2, row_start, csr_src, alpha2, E, N);
  gat_agg_slice<128><<<aggblocks, 256, 0, stream>>>(
      h2s, alpha2, row_start, csr_src, nodeord, bnsc2, bnsh2, nullptr, o2f, E, N);
  // layer 3 prep + aggregation + log_softmax
  l3_prep_kernel<<<nodes4, 256, 0, stream>>>(o2f, W3, a3s, a3d, (float4*)h3p, ald3, N);
  l3_agg_kernel<<<nodes4, 256, 0, stream>>>((const float4*)h3p, ald3, row_start, csr_src,
                                            b3, out, N);
}

// Round 9
// 427.967 us; speedup vs baseline: 1.7389x; 1.1023x over previous
//
#include <hip/hip_runtime.h>

// ---------------------------------------------------------------------------
// DoshaGAT: 3-layer GAT. R13 (consolidation):
//  - Sliced agg (XCD %8, slice-major h, folded BN) with LDS-STAGED edge
//    stream: block stages its contiguous csr range as (s, als[s]) pairs into
//    LDS (coalesced csr + batched als gathers); per-node loop computes
//    exp(leaky(.)) inline and normalizes by ssum in the epilogue. The hot
//    loop's only global access is the L2-resident h gather.
//  - alpha kernels/planes and the degree sort are DELETED (R12: sort
//    destroyed stream locality, FETCH 82->183MB; alpha passes cost ~60us).
//  - Natural node order restored (contiguous staging ranges).
//  - GEMM, l3_prep, l3_agg, CSR build verbatim from R12.
// ---------------------------------------------------------------------------

#define WSZ 64

typedef short short8 __attribute__((ext_vector_type(8)));
typedef short short4v __attribute__((ext_vector_type(4)));
typedef float float4v __attribute__((ext_vector_type(4)));
typedef float f2v __attribute__((ext_vector_type(2)));
typedef unsigned uint2v __attribute__((ext_vector_type(2)));

__device__ inline unsigned short f2bf(float f) {  // RNE f32->bf16
  unsigned u = __float_as_uint(f);
  u += 0x7FFFu + ((u >> 16) & 1u);
  return (unsigned short)(u >> 16);
}
__device__ inline float bf2f(unsigned short u) {
  return __uint_as_float(((unsigned)u) << 16);
}

// ---------------- CSR build ----------------

__global__ __launch_bounds__(256) void hist_kernel(const int* __restrict__ dst, int E,
                                                   int* __restrict__ deg) {
  int e = blockIdx.x * 256 + threadIdx.x;
  if (e < E) atomicAdd(&deg[dst[e]], 1);
}

__global__ __launch_bounds__(256) void block_sums_kernel(const int* __restrict__ deg, int n,
                                                         int* __restrict__ bsum) {
  __shared__ int sh[256];
  int t = threadIdx.x;
  int base = blockIdx.x * 1024 + t * 4;
  int v = 0;
#pragma unroll
  for (int j = 0; j < 4; ++j) {
    int idx = base + j;
    if (idx < n) v += deg[idx];
  }
  sh[t] = v;
  __syncthreads();
  for (int off = 128; off >= 1; off >>= 1) {
    if (t < off) sh[t] += sh[t + off];
    __syncthreads();
  }
  if (t == 0) bsum[blockIdx.x] = sh[0];
}

__global__ void tiny_scan_kernel(int* bsum, int nb) {
  if (threadIdx.x == 0 && blockIdx.x == 0) {
    int run = 0;
    for (int i = 0; i < nb; ++i) {
      int v = bsum[i];
      bsum[i] = run;
      run += v;
    }
  }
}

__global__ __launch_bounds__(256) void scan_write_kernel(const int* __restrict__ deg, int n,
                                                         const int* __restrict__ bbase,
                                                         int* __restrict__ row_start,
                                                         int* __restrict__ cursor) {
  __shared__ int sh[256];
  int t = threadIdx.x;
  int base = blockIdx.x * 1024 + t * 4;
  int v[4];
  int s = 0;
#pragma unroll
  for (int j = 0; j < 4; ++j) {
    int idx = base + j;
    v[j] = (idx < n) ? deg[idx] : 0;
    s += v[j];
  }
  sh[t] = s;
  __syncthreads();
  for (int off = 1; off < 256; off <<= 1) {
    int x = (t >= off) ? sh[t - off] : 0;
    __syncthreads();
    sh[t] += x;
    __syncthreads();
  }
  int excl = sh[t] - s + bbase[blockIdx.x];
#pragma unroll
  for (int j = 0; j < 4; ++j) {
    int idx = base + j;
    if (idx < n) {
      row_start[idx] = excl;
      cursor[idx] = excl;
    }
    excl += v[j];
  }
  if (blockIdx.x == gridDim.x - 1 && t == 255) row_start[n] = excl;  // == E
}

__global__ __launch_bounds__(256) void scatter_kernel(const int* __restrict__ src,
                                                      const int* __restrict__ dst, int E,
                                                      int* __restrict__ cursor,
                                                      int* __restrict__ csr_src) {
  int e = blockIdx.x * 256 + threadIdx.x;
  if (e < E) {
    int d = dst[e];
    int p = atomicAdd(&cursor[d], 1);
    csr_src[p] = src[e];
  }
}

// ---------------- weight conversion + BN fold ----------------

// W1 [128][256] -> W1t [256][128] bf16
__global__ __launch_bounds__(256) void conv_w1t_kernel(const float* __restrict__ W1,
                                                       unsigned short* __restrict__ W1t) {
  int idx = blockIdx.x * 256 + threadIdx.x;  // 32768
  int n = idx >> 7, k = idx & 127;
  W1t[idx] = f2bf(W1[k * 256 + n]);
}

// W2 [256][128] -> W2t [128][256] bf16, K rows permuted to layer-1 phys layout
__global__ __launch_bounds__(256) void conv_w2t_kernel(const float* __restrict__ W2,
                                                       unsigned short* __restrict__ W2t) {
  int idx = blockIdx.x * 256 + threadIdx.x;  // 32768
  int n = idx >> 8, p = idx & 255;
  int kl = (p & ~63) | ((p & 3) << 4) | ((p >> 2) & 15);
  W2t[idx] = f2bf(W2[kl * 128 + n]);
}

// fold bias+BN into per-logical-col scale/shift: o*sc + sh
__global__ __launch_bounds__(512) void bn_prep_kernel(
    const float* __restrict__ b1, const float* __restrict__ g1,
    const float* __restrict__ be1, const float* __restrict__ m1,
    const float* __restrict__ v1, const float* __restrict__ b2,
    const float* __restrict__ g2, const float* __restrict__ be2,
    const float* __restrict__ m2, const float* __restrict__ v2,
    float* __restrict__ sc1, float* __restrict__ sh1,
    float* __restrict__ sc2, float* __restrict__ sh2) {
  int t = threadIdx.x;
  if (t < 256) {
    float s = g1[t] * rsqrtf(v1[t] + 1e-5f);
    sc1[t] = s;
    sh1[t] = (b1[t] - m1[t]) * s + be1[t];
  } else if (t < 384) {
    int i = t - 256;
    float s = g2[i] * rsqrtf(v2[i] + 1e-5f);
    sc2[i] = s;
    sh2[i] = (b2[i] - m2[i]) * s + be2[i];
  }
}

// ---------------- bf16 MFMA GEMM + fused attn-coeff epilogue ----------------
// C[M,BN] = A[M,K] @ B[K,BN]. 64-row blocks, 256 threads, 4 waves (wave=head).
// AF32: A is f32, converted to bf16 during LDS staging.
// hout is written SLICE-MAJOR: 8 subtables of [M][BN/8] bf16.

template <int K, int BN, bool AF32>
__global__ __launch_bounds__(256) void gemm_mfma(
    const void* __restrict__ Ap,            // [M][K] bf16 or f32
    const unsigned short* __restrict__ Bt,  // [BN][K] bf16 (pre-transposed)
    const float* __restrict__ a_s, const float* __restrict__ a_d,  // [BN] logical
    unsigned short* __restrict__ hout,      // slice-major output
    float* __restrict__ als, float* __restrict__ ald,  // [M][4]
    int M) {
  constexpr int CF = BN / 64;  // col frags per wave
  constexpr int SF = BN / 8;   // feats per slice (32 or 16)
  constexpr int PAD = 36;
  __shared__ unsigned short As[64][PAD];
  __shared__ unsigned short Bs[BN][PAD];
  const int t = threadIdx.x;
  const int w = t >> 6;
  const int lane = t & 63;
  const int c16 = lane & 15;
  const int q = lane >> 4;
  const int bm = blockIdx.x * 64;
  const int arow = t >> 2;      // 0..63
  const int akc = (t & 3) * 8;  // 0,8,16,24

  float4v acc[4][CF];
#pragma unroll
  for (int rf = 0; rf < 4; ++rf)
#pragma unroll
    for (int cf = 0; cf < CF; ++cf) acc[rf][cf] = float4v{0.f, 0.f, 0.f, 0.f};

  for (int k0 = 0; k0 < K; k0 += 32) {
    {  // stage A tile 64x32 (8 elems/thread)
      int gr = bm + arow;
      if constexpr (AF32) {
        const float* Af = (const float*)Ap + (size_t)gr * K + k0 + akc;
        float4 v0 = make_float4(0.f, 0.f, 0.f, 0.f), v1 = v0;
        if (gr < M) {
          v0 = *(const float4*)Af;
          v1 = *(const float4*)(Af + 4);
        }
        ushort4 u0, u1;
        u0.x = f2bf(v0.x); u0.y = f2bf(v0.y); u0.z = f2bf(v0.z); u0.w = f2bf(v0.w);
        u1.x = f2bf(v1.x); u1.y = f2bf(v1.y); u1.z = f2bf(v1.z); u1.w = f2bf(v1.w);
        *(ushort4*)&As[arow][akc] = u0;
        *(ushort4*)&As[arow][akc + 4] = u1;
      } else {
        uint4 v = make_uint4(0u, 0u, 0u, 0u);
        if (gr < M) v = *(const uint4*)((const unsigned short*)Ap + (size_t)gr * K + k0 + akc);
        *(uint2*)&As[arow][akc] = make_uint2(v.x, v.y);
        *(uint2*)&As[arow][akc + 4] = make_uint2(v.z, v.w);
      }
    }
#pragma unroll
    for (int h = 0; h < BN / 64; ++h) {  // stage B tile BNx32
      int n = (t >> 2) + h * 64;
      uint4 v = *(const uint4*)(Bt + (size_t)n * K + k0 + akc);
      *(uint2*)&Bs[n][akc] = make_uint2(v.x, v.y);
      *(uint2*)&Bs[n][akc + 4] = make_uint2(v.z, v.w);
    }
    __syncthreads();
    short8 af[4], bfr[CF];
#pragma unroll
    for (int rf = 0; rf < 4; ++rf) {
      short4v lo = *(short4v*)&As[rf * 16 + c16][q * 8];
      short4v hi = *(short4v*)&As[rf * 16 + c16][q * 8 + 4];
      af[rf] = __builtin_shufflevector(lo, hi, 0, 1, 2, 3, 4, 5, 6, 7);
    }
#pragma unroll
    for (int cf = 0; cf < CF; ++cf) {
      int n = w * (CF * 16) + cf * 16 + c16;
      short4v lo = *(short4v*)&Bs[n][q * 8];
      short4v hi = *(short4v*)&Bs[n][q * 8 + 4];
      bfr[cf] = __builtin_shufflevector(lo, hi, 0, 1, 2, 3, 4, 5, 6, 7);
    }
#pragma unroll
    for (int rf = 0; rf < 4; ++rf)
#pragma unroll
      for (int cf = 0; cf < CF; ++cf)
        acc[rf][cf] =
            __builtin_amdgcn_mfma_f32_16x16x32_bf16(af[rf], bfr[cf], acc[rf][cf], 0, 0, 0);
    __syncthreads();
  }

  float sasv[CF], sadv[CF];
#pragma unroll
  for (int cf = 0; cf < CF; ++cf) {
    int L = w * (CF * 16) + cf * 16 + c16;
    sasv[cf] = a_s[L];
    sadv[cf] = a_d[L];
  }
  // slice-major store base: subtable = w*2 + (c16>>3)
  const size_t sub = (size_t)(w * 2 + (c16 >> 3)) * (size_t)M * SF;
#pragma unroll
  for (int rf = 0; rf < 4; ++rf) {
#pragma unroll
    for (int r = 0; r < 4; ++r) {
      int n = bm + rf * 16 + q * 4 + r;
      float ps = 0.f, pd = 0.f;
      unsigned short us[CF];
#pragma unroll
      for (int cf = 0; cf < CF; ++cf) {
        float v = acc[rf][cf][r];
        us[cf] = f2bf(v);
        ps += v * sasv[cf];
        pd += v * sadv[cf];
      }
#pragma unroll
      for (int off = 1; off <= 8; off <<= 1) {
        ps += __shfl_xor(ps, off, 16);
        pd += __shfl_xor(pd, off, 16);
      }
      if (n < M) {
        if constexpr (CF == 4) {
          ushort4 u;
          u.x = us[0]; u.y = us[1]; u.z = us[2]; u.w = us[3];
          *(ushort4*)(hout + sub + (size_t)n * 32 + (c16 & 7) * 4) = u;
        } else {
          ushort2 u;
          u.x = us[0]; u.y = us[1];
          *(ushort2*)(hout + sub + (size_t)n * 16 + (c16 & 7) * 2) = u;
        }
        if (c16 == 0) {
          als[(size_t)n * 4 + w] = ps;
          ald[(size_t)n * 4 + w] = pd;
        }
      }
    }
  }
}

// ---------------- XCD-sliced GAT agg, LDS-staged edges, fused softmax -------
// slice = blockIdx%8 -> XCD; block = 32 consecutive nodes; stage (s, als[s])
// for the block's contiguous csr range into LDS; per-node loop: exp inline,
// h gather (L2-resident slice) is the only global access; normalize by ssum
// in epilogue, then folded-BN + ELU + nt store.

template <int D>
__global__ __launch_bounds__(256) void gat_agg_slice(
    const unsigned short* __restrict__ h_sl,  // 8 slice-major subtables
    const float* __restrict__ als, const float* __restrict__ ald,  // [N][4]
    const int* __restrict__ row_start, const int* __restrict__ csr_src,
    const float* __restrict__ bnsc, const float* __restrict__ bnsh,  // [D] logical
    unsigned short* __restrict__ obf,  // D==256 out (bf16 phys rows)
    float* __restrict__ of32,          // D==128 out (f32 phys rows)
    int n_nodes) {
  constexpr int SFEAT = D / 8;   // 32 | 16
  constexpr int KF = SFEAT / 8;  // feats per lane: 4 | 2
  constexpr int CAP = 1280;      // staged edges (mean 544, +32 sigma)
  __shared__ int s_s[CAP];
  __shared__ float s_a[CAP];
  const int sl = blockIdx.x & 7;
  const int g = blockIdx.x >> 3;
  const int tid = threadIdx.x;
  const int wid = tid >> 6, lane = tid & 63;
  const int f = lane & 7;    // feat slot
  const int ng = lane >> 3;  // node sub-slot 0..7
  const int head = sl >> 1;
  const char* hb = (const char*)(h_sl + (size_t)sl * (unsigned)n_nodes * SFEAT);
  const unsigned uoff = (unsigned)(f * KF * 2);  // byte off in slice row

  const int nb0 = g * 32;
  int rs = __builtin_amdgcn_readfirstlane(row_start[nb0]);
  int re = __builtin_amdgcn_readfirstlane(row_start[min(nb0 + 32, n_nodes)]);
  const bool fast = (re - rs) <= CAP;
  if (fast) {
    for (int i = rs + tid; i < re; i += 256) {
      int s = csr_src[i];
      s_s[i - rs] = s;
      s_a[i - rs] = als[(size_t)(unsigned)s * 4 + head];
    }
  }
  __syncthreads();

  // folded BN constants for this lane's logical cols
  const int lb = (D == 256 ? head * 64 : head * 32) + (sl & 1) * 8 + f;
  float sc0 = bnsc[lb], sh0v = bnsh[lb];
  float sc1 = bnsc[lb + 16], sh1v = bnsh[lb + 16];
  float sc2 = 0.f, sh2v = 0.f, sc3 = 0.f, sh3v = 0.f;
  if constexpr (D == 256) {
    sc2 = bnsc[lb + 32]; sh2v = bnsh[lb + 32];
    sc3 = bnsc[lb + 48]; sh3v = bnsh[lb + 48];
  }

  int n = nb0 + wid * 8 + ng;
  bool valid = n < n_nodes;
  int row = valid ? row_start[n] : rs;
  int deg = valid ? (row_start[n + 1] - row) : 0;
  float aldv = ald[(size_t)(unsigned)(valid ? n : 0) * 4 + head];
  int mx = deg;
#pragma unroll
  for (int off = 8; off <= 32; off <<= 1) mx = max(mx, __shfl_xor(mx, off, 64));
  mx = __builtin_amdgcn_readfirstlane(mx);

  float acc0 = 0.f, acc1 = 0.f, acc2 = 0.f, acc3 = 0.f, ssum = 0.f;

#define AGG_BODY(SGET, AGET)                                        \
  {                                                                 \
    bool act = j < deg;                                             \
    int jo = act ? j : 0;                                           \
    int s = (SGET);                                                 \
    float av = (AGET);                                              \
    float e = av + aldv;                                            \
    e = fmaxf(e, 0.2f * e);                                         \
    float ex = __expf(e);                                           \
    ex = act ? ex : 0.f;                                            \
    ssum += ex;                                                     \
    if constexpr (D == 256) {                                       \
      uint2v u = *(const uint2v*)(hb + ((unsigned)s * 64u + uoff)); \
      acc0 += ex * __uint_as_float(u.x << 16);                      \
      acc1 += ex * __uint_as_float(u.x & 0xffff0000u);              \
      acc2 += ex * __uint_as_float(u.y << 16);                      \
      acc3 += ex * __uint_as_float(u.y & 0xffff0000u);              \
    } else {                                                        \
      unsigned u = *(const unsigned*)(hb + ((unsigned)s * 32u + uoff)); \
      acc0 += ex * __uint_as_float(u << 16);                        \
      acc1 += ex * __uint_as_float(u & 0xffff0000u);                \
    }                                                               \
  }

  if (fast) {
    int base = row - rs;
#pragma unroll 4
    for (int j = 0; j < mx; ++j) AGG_BODY(s_s[base + jo], s_a[base + jo])
  } else {
#pragma unroll 2
    for (int j = 0; j < mx; ++j)
      AGG_BODY(csr_src[row + jo], als[(size_t)(unsigned)s * 4 + head])
  }
#undef AGG_BODY

  if (valid) {
    float inv = 1.f / (ssum + 1e-16f);
    if constexpr (D == 256) {
      float o0 = acc0 * inv, o1 = acc1 * inv, o2 = acc2 * inv, o3 = acc3 * inv;
      float v0 = o0 * sc0 + sh0v;
      float v1 = o1 * sc1 + sh1v;
      float v2 = o2 * sc2 + sh2v;
      float v3 = o3 * sc3 + sh3v;
      v0 = (v0 > 0.f) ? v0 : (__expf(v0) - 1.f);
      v1 = (v1 > 0.f) ? v1 : (__expf(v1) - 1.f);
      v2 = (v2 > 0.f) ? v2 : (__expf(v2) - 1.f);
      v3 = (v3 > 0.f) ? v3 : (__expf(v3) - 1.f);
      uint2v pk;
      pk.x = (unsigned)f2bf(v0) | ((unsigned)f2bf(v1) << 16);
      pk.y = (unsigned)f2bf(v2) | ((unsigned)f2bf(v3) << 16);
      __builtin_nontemporal_store(
          pk, (uint2v*)(obf + (size_t)n * 256 + sl * 32 + f * 4));
    } else {
      float o0 = acc0 * inv, o1 = acc1 * inv;
      float v0 = o0 * sc0 + sh0v;
      float v1 = o1 * sc1 + sh1v;
      v0 = (v0 > 0.f) ? v0 : (__expf(v0) - 1.f);
      v1 = (v1 > 0.f) ? v1 : (__expf(v1) - 1.f);
      f2v v2;
      v2.x = v0; v2.y = v1;
      __builtin_nontemporal_store(
          v2, (f2v*)(of32 + (size_t)n * 128 + sl * 16 + f * 2));
    }
  }
}

// ---------------- layer-3 prep: h3 = o2 @ W3, als3/ald3 ---------------------

__global__ __launch_bounds__(256) void l3_prep_kernel(
    const float* __restrict__ o2, const float* __restrict__ W3,
    const float* __restrict__ a3s, const float* __restrict__ a3d,
    float4* __restrict__ h3p, float* __restrict__ ald3, int n_nodes) {
  __shared__ float w3s[384];
  __shared__ float sa3[6];
  for (int i = threadIdx.x; i < 384; i += 256) w3s[i] = W3[i];
  if (threadIdx.x < 3) {
    sa3[threadIdx.x] = a3s[threadIdx.x];
    sa3[3 + threadIdx.x] = a3d[threadIdx.x];
  }
  __syncthreads();
  int wid = threadIdx.x >> 6, lane = threadIdx.x & 63;
  int n = blockIdx.x * 4 + wid;
  if (n >= n_nodes) return;
  f2v v = *(const f2v*)(o2 + (size_t)n * 128 + lane * 2);  // phys cols lane*2,+1
  int hd = lane >> 4;
  int k0l = hd * 32 + (lane & 15);  // logical k of phys col lane*2
  int k1l = k0l + 16;               // logical k of phys col lane*2+1
  float p0 = v.x * w3s[k0l * 3 + 0] + v.y * w3s[k1l * 3 + 0];
  float p1 = v.x * w3s[k0l * 3 + 1] + v.y * w3s[k1l * 3 + 1];
  float p2 = v.x * w3s[k0l * 3 + 2] + v.y * w3s[k1l * 3 + 2];
#pragma unroll
  for (int off = 32; off >= 1; off >>= 1) {
    p0 += __shfl_xor(p0, off, 64);
    p1 += __shfl_xor(p1, off, 64);
    p2 += __shfl_xor(p2, off, 64);
  }
  if (lane == 0) {
    float als3 = p0 * sa3[0] + p1 * sa3[1] + p2 * sa3[2];
    float ad3 = p0 * sa3[3] + p1 * sa3[4] + p2 * sa3[5];
    h3p[n] = make_float4(p0, p1, p2, als3);
    ald3[n] = ad3;
  }
}

// ---------------- layer 3 aggregation + log_softmax -------------------------

__global__ __launch_bounds__(256) void l3_agg_kernel(const float4* __restrict__ h3p,
                                                     const float* __restrict__ ald3,
                                                     const int* __restrict__ row_start,
                                                     const int* __restrict__ csr_src,
                                                     const float* __restrict__ b3,
                                                     float* __restrict__ out, int n_nodes) {
  int wid = threadIdx.x >> 6, lane = threadIdx.x & 63;
  int n = __builtin_amdgcn_readfirstlane(blockIdx.x * 4 + wid);
  if (n >= n_nodes) return;
  float aldv = ald3[n];
  int row = __builtin_amdgcn_readfirstlane(row_start[n]);
  int end = __builtin_amdgcn_readfirstlane(row_start[n + 1]);
  const char* hp = (const char*)h3p;
  float a0 = 0.f, a1 = 0.f, a2 = 0.f, ss = 0.f;
  for (int i = row + lane; i < end; i += 64) {
    int s = csr_src[i];
    float4 hv = *(const float4*)(hp + ((unsigned)s * 16u));
    float e = hv.w + aldv;
    e = fmaxf(e, 0.2f * e);
    float ex = __expf(e);
    ss += ex;
    a0 += ex * hv.x;
    a1 += ex * hv.y;
    a2 += ex * hv.z;
  }
#pragma unroll
  for (int off = 32; off >= 1; off >>= 1) {
    a0 += __shfl_xor(a0, off, 64);
    a1 += __shfl_xor(a1, off, 64);
    a2 += __shfl_xor(a2, off, 64);
    ss += __shfl_xor(ss, off, 64);
  }
  if (lane == 0) {
    float inv = 1.f / (ss + 1e-16f);
    float o0 = a0 * inv + b3[0];
    float o1 = a1 * inv + b3[1];
    float o2 = a2 * inv + b3[2];
    float m = fmaxf(o0, fmaxf(o1, o2));
    float lse = m + logf(expf(o0 - m) + expf(o1 - m) + expf(o2 - m));
    out[n * 3 + 0] = o0 - lse;
    out[n * 3 + 1] = o1 - lse;
    out[n * 3 + 2] = o2 - lse;
  }
}

// ---------------------------------------------------------------------------

extern "C" void kernel_launch(void* const* d_in, const int* in_sizes, int n_in,
                              void* d_out, int out_size, void* d_ws, size_t ws_size,
                              hipStream_t stream) {
  const float* x   = (const float*)d_in[0];
  const int*   ei  = (const int*)d_in[1];
  const float* W1  = (const float*)d_in[2];
  const float* a1s = (const float*)d_in[3];
  const float* a1d = (const float*)d_in[4];
  const float* b1  = (const float*)d_in[5];
  const float* g1v = (const float*)d_in[6];
  const float* be1 = (const float*)d_in[7];
  const float* m1  = (const float*)d_in[8];
  const float* v1  = (const float*)d_in[9];
  const float* W2  = (const float*)d_in[10];
  const float* a2s = (const float*)d_in[11];
  const float* a2d = (const float*)d_in[12];
  const float* b2  = (const float*)d_in[13];
  const float* g2v = (const float*)d_in[14];
  const float* be2 = (const float*)d_in[15];
  const float* m2  = (const float*)d_in[16];
  const float* v2  = (const float*)d_in[17];
  const float* W3  = (const float*)d_in[18];
  const float* a3s = (const float*)d_in[19];
  const float* a3d = (const float*)d_in[20];
  const float* b3  = (const float*)d_in[21];
  float* out = (float*)d_out;

  const int N = in_sizes[0] / 128;  // 50000
  const int E = in_sizes[1] / 2;    // 850000
  const int* srcv = ei;
  const int* dstv = ei + E;

  const int eb = (E + 255) / 256;
  const int nb = (N + 1023) / 1024;
  const int nodes4 = (N + 3) / 4;
  const int mblocks = (N + 63) / 64;
  const int aggblocks = ((N + 31) / 32) * 8;  // 32 nodes/block x 8 slices

  // workspace carve-up (~60 MB)
  float* wsf  = (float*)d_ws;
  float* als1 = wsf;                   // N*4
  float* ald1 = als1 + (size_t)N * 4;
  float* als2 = ald1 + (size_t)N * 4;
  float* ald2 = als2 + (size_t)N * 4;
  float* h3p  = ald2 + (size_t)N * 4;  // N*4 (float4 rows)
  float* ald3 = h3p + (size_t)N * 4;   // N
  unsigned short* h1s   = (unsigned short*)(ald3 + N);  // N*256 (8 subtables N*32)
  unsigned short* o1_bf = h1s + (size_t)N * 256;        // N*256 row-major phys
  unsigned short* W1t   = o1_bf + (size_t)N * 256;      // 256*128
  unsigned short* W2t   = W1t + 256 * 128;              // 128*256
  int* deg       = (int*)(W2t + 128 * 256);  // N
  int* row_start = deg + N;                  // N+1
  int* cursor    = row_start + (N + 1);      // N+1
  int* csr_src   = cursor + (N + 1);         // E
  int* bsum      = csr_src + E;              // 1024
  float* bnsc1 = (float*)(bsum + 1024);      // 256
  float* bnsh1 = bnsc1 + 256;                // 256
  float* bnsc2 = bnsh1 + 256;                // 128
  float* bnsh2 = bnsc2 + 128;                // 128
  unsigned short* h2s = (unsigned short*)(bnsh2 + 128);  // N*128 (8 subtables N*16)
  // alias (lifetimes disjoint): o2 f32 reuses h1s (dead after agg1)
  float* o2f = (float*)h1s;  // N*128 f32

  // weight conversions + BN fold
  conv_w1t_kernel<<<128, 256, 0, stream>>>(W1, W1t);
  conv_w2t_kernel<<<128, 256, 0, stream>>>(W2, W2t);
  bn_prep_kernel<<<1, 512, 0, stream>>>(b1, g1v, be1, m1, v1, b2, g2v, be2, m2, v2,
                                        bnsc1, bnsh1, bnsc2, bnsh2);

  // CSR build (shared by all 3 layers)
  hipMemsetAsync(deg, 0, (size_t)N * sizeof(int), stream);
  hist_kernel<<<eb, 256, 0, stream>>>(dstv, E, deg);
  block_sums_kernel<<<nb, 256, 0, stream>>>(deg, N, bsum);
  tiny_scan_kernel<<<1, 64, 0, stream>>>(bsum, nb);
  scan_write_kernel<<<nb, 256, 0, stream>>>(deg, N, bsum, row_start, cursor);
  scatter_kernel<<<eb, 256, 0, stream>>>(srcv, dstv, E, cursor, csr_src);

  // layer 1
  gemm_mfma<128, 256, true><<<mblocks, 256, 0, stream>>>(x, W1t, a1s, a1d, h1s, als1,
                                                         ald1, N);
  gat_agg_slice<256><<<aggblocks, 256, 0, stream>>>(
      h1s, als1, ald1, row_start, csr_src, bnsc1, bnsh1, o1_bf, nullptr, N);
  // layer 2
  gemm_mfma<256, 128, false><<<mblocks, 256, 0, stream>>>(o1_bf, W2t, a2s, a2d, h2s, als2,
                                                          ald2, N);
  gat_agg_slice<128><<<aggblocks, 256, 0, stream>>>(
      h2s, als2, ald2, row_start, csr_src, bnsc2, bnsh2, nullptr, o2f, N);
  // layer 3 prep + aggregation + log_softmax
  l3_prep_kernel<<<nodes4, 256, 0, stream>>>(o2f, W3, a3s, a3d, (float4*)h3p, ald3, N);
  l3_agg_kernel<<<nodes4, 256, 0, stream>>>((const float4*)h3p, ald3, row_start, csr_src,
                                            b3, out, N);
}

// Round 10
// 424.197 us; speedup vs baseline: 1.7544x; 1.0089x over previous
//
#include <hip/hip_runtime.h>

// ---------------------------------------------------------------------------
// DoshaGAT: 3-layer GAT. R14 (= R13 +):
//  - Staging computes UNNORMALIZED softmax coeffs: s_a[i] = exp(leaky(
//    als[s]+ald[dst(i)])), dst via 5-step binary search on LDS row bounds.
//    Hot loop is now {s,ex LDS reads + gather + unpack/FMA + ssum} only —
//    removes the 8x-per-slice inline exp chain (the dominant VALU cost).
//  - agg2 (D=128) runs 4 slices (slice=head, 32 cols, ws 3.2MB L2-fit);
//    8 XCD slots = (head, node-half) pairs so per-XCD table slice is fixed.
//    o2 stored as float4.
//  - Everything else verbatim from R13.
// ---------------------------------------------------------------------------

#define WSZ 64

typedef short short8 __attribute__((ext_vector_type(8)));
typedef short short4v __attribute__((ext_vector_type(4)));
typedef float float4v __attribute__((ext_vector_type(4)));
typedef float f2v __attribute__((ext_vector_type(2)));
typedef float f4v __attribute__((ext_vector_type(4)));
typedef unsigned uint2v __attribute__((ext_vector_type(2)));

__device__ inline unsigned short f2bf(float f) {  // RNE f32->bf16
  unsigned u = __float_as_uint(f);
  u += 0x7FFFu + ((u >> 16) & 1u);
  return (unsigned short)(u >> 16);
}
__device__ inline float bf2f(unsigned short u) {
  return __uint_as_float(((unsigned)u) << 16);
}

// ---------------- CSR build ----------------

__global__ __launch_bounds__(256) void hist_kernel(const int* __restrict__ dst, int E,
                                                   int* __restrict__ deg) {
  int e = blockIdx.x * 256 + threadIdx.x;
  if (e < E) atomicAdd(&deg[dst[e]], 1);
}

__global__ __launch_bounds__(256) void block_sums_kernel(const int* __restrict__ deg, int n,
                                                         int* __restrict__ bsum) {
  __shared__ int sh[256];
  int t = threadIdx.x;
  int base = blockIdx.x * 1024 + t * 4;
  int v = 0;
#pragma unroll
  for (int j = 0; j < 4; ++j) {
    int idx = base + j;
    if (idx < n) v += deg[idx];
  }
  sh[t] = v;
  __syncthreads();
  for (int off = 128; off >= 1; off >>= 1) {
    if (t < off) sh[t] += sh[t + off];
    __syncthreads();
  }
  if (t == 0) bsum[blockIdx.x] = sh[0];
}

__global__ void tiny_scan_kernel(int* bsum, int nb) {
  if (threadIdx.x == 0 && blockIdx.x == 0) {
    int run = 0;
    for (int i = 0; i < nb; ++i) {
      int v = bsum[i];
      bsum[i] = run;
      run += v;
    }
  }
}

__global__ __launch_bounds__(256) void scan_write_kernel(const int* __restrict__ deg, int n,
                                                         const int* __restrict__ bbase,
                                                         int* __restrict__ row_start,
                                                         int* __restrict__ cursor) {
  __shared__ int sh[256];
  int t = threadIdx.x;
  int base = blockIdx.x * 1024 + t * 4;
  int v[4];
  int s = 0;
#pragma unroll
  for (int j = 0; j < 4; ++j) {
    int idx = base + j;
    v[j] = (idx < n) ? deg[idx] : 0;
    s += v[j];
  }
  sh[t] = s;
  __syncthreads();
  for (int off = 1; off < 256; off <<= 1) {
    int x = (t >= off) ? sh[t - off] : 0;
    __syncthreads();
    sh[t] += x;
    __syncthreads();
  }
  int excl = sh[t] - s + bbase[blockIdx.x];
#pragma unroll
  for (int j = 0; j < 4; ++j) {
    int idx = base + j;
    if (idx < n) {
      row_start[idx] = excl;
      cursor[idx] = excl;
    }
    excl += v[j];
  }
  if (blockIdx.x == gridDim.x - 1 && t == 255) row_start[n] = excl;  // == E
}

__global__ __launch_bounds__(256) void scatter_kernel(const int* __restrict__ src,
                                                      const int* __restrict__ dst, int E,
                                                      int* __restrict__ cursor,
                                                      int* __restrict__ csr_src) {
  int e = blockIdx.x * 256 + threadIdx.x;
  if (e < E) {
    int d = dst[e];
    int p = atomicAdd(&cursor[d], 1);
    csr_src[p] = src[e];
  }
}

// ---------------- weight conversion + BN fold ----------------

// W1 [128][256] -> W1t [256][128] bf16
__global__ __launch_bounds__(256) void conv_w1t_kernel(const float* __restrict__ W1,
                                                       unsigned short* __restrict__ W1t) {
  int idx = blockIdx.x * 256 + threadIdx.x;  // 32768
  int n = idx >> 7, k = idx & 127;
  W1t[idx] = f2bf(W1[k * 256 + n]);
}

// W2 [256][128] -> W2t [128][256] bf16, K rows permuted to layer-1 phys layout
__global__ __launch_bounds__(256) void conv_w2t_kernel(const float* __restrict__ W2,
                                                       unsigned short* __restrict__ W2t) {
  int idx = blockIdx.x * 256 + threadIdx.x;  // 32768
  int n = idx >> 8, p = idx & 255;
  int kl = (p & ~63) | ((p & 3) << 4) | ((p >> 2) & 15);
  W2t[idx] = f2bf(W2[kl * 128 + n]);
}

// fold bias+BN into per-logical-col scale/shift: o*sc + sh
__global__ __launch_bounds__(512) void bn_prep_kernel(
    const float* __restrict__ b1, const float* __restrict__ g1,
    const float* __restrict__ be1, const float* __restrict__ m1,
    const float* __restrict__ v1, const float* __restrict__ b2,
    const float* __restrict__ g2, const float* __restrict__ be2,
    const float* __restrict__ m2, const float* __restrict__ v2,
    float* __restrict__ sc1, float* __restrict__ sh1,
    float* __restrict__ sc2, float* __restrict__ sh2) {
  int t = threadIdx.x;
  if (t < 256) {
    float s = g1[t] * rsqrtf(v1[t] + 1e-5f);
    sc1[t] = s;
    sh1[t] = (b1[t] - m1[t]) * s + be1[t];
  } else if (t < 384) {
    int i = t - 256;
    float s = g2[i] * rsqrtf(v2[i] + 1e-5f);
    sc2[i] = s;
    sh2[i] = (b2[i] - m2[i]) * s + be2[i];
  }
}

// ---------------- bf16 MFMA GEMM + fused attn-coeff epilogue ----------------
// C[M,BN] = A[M,K] @ B[K,BN]. 64-row blocks, 256 threads, 4 waves (wave=head).
// AF32: A is f32, converted to bf16 during LDS staging.
// hout is written SLICE-MAJOR: 8 subtables of [M][BN/8] bf16.

template <int K, int BN, bool AF32>
__global__ __launch_bounds__(256) void gemm_mfma(
    const void* __restrict__ Ap,            // [M][K] bf16 or f32
    const unsigned short* __restrict__ Bt,  // [BN][K] bf16 (pre-transposed)
    const float* __restrict__ a_s, const float* __restrict__ a_d,  // [BN] logical
    unsigned short* __restrict__ hout,      // slice-major output
    float* __restrict__ als, float* __restrict__ ald,  // [M][4]
    int M) {
  constexpr int CF = BN / 64;  // col frags per wave
  constexpr int SF = BN / 8;   // feats per slice (32 or 16)
  constexpr int PAD = 36;
  __shared__ unsigned short As[64][PAD];
  __shared__ unsigned short Bs[BN][PAD];
  const int t = threadIdx.x;
  const int w = t >> 6;
  const int lane = t & 63;
  const int c16 = lane & 15;
  const int q = lane >> 4;
  const int bm = blockIdx.x * 64;
  const int arow = t >> 2;      // 0..63
  const int akc = (t & 3) * 8;  // 0,8,16,24

  float4v acc[4][CF];
#pragma unroll
  for (int rf = 0; rf < 4; ++rf)
#pragma unroll
    for (int cf = 0; cf < CF; ++cf) acc[rf][cf] = float4v{0.f, 0.f, 0.f, 0.f};

  for (int k0 = 0; k0 < K; k0 += 32) {
    {  // stage A tile 64x32 (8 elems/thread)
      int gr = bm + arow;
      if constexpr (AF32) {
        const float* Af = (const float*)Ap + (size_t)gr * K + k0 + akc;
        float4 v0 = make_float4(0.f, 0.f, 0.f, 0.f), v1 = v0;
        if (gr < M) {
          v0 = *(const float4*)Af;
          v1 = *(const float4*)(Af + 4);
        }
        ushort4 u0, u1;
        u0.x = f2bf(v0.x); u0.y = f2bf(v0.y); u0.z = f2bf(v0.z); u0.w = f2bf(v0.w);
        u1.x = f2bf(v1.x); u1.y = f2bf(v1.y); u1.z = f2bf(v1.z); u1.w = f2bf(v1.w);
        *(ushort4*)&As[arow][akc] = u0;
        *(ushort4*)&As[arow][akc + 4] = u1;
      } else {
        uint4 v = make_uint4(0u, 0u, 0u, 0u);
        if (gr < M) v = *(const uint4*)((const unsigned short*)Ap + (size_t)gr * K + k0 + akc);
        *(uint2*)&As[arow][akc] = make_uint2(v.x, v.y);
        *(uint2*)&As[arow][akc + 4] = make_uint2(v.z, v.w);
      }
    }
#pragma unroll
    for (int h = 0; h < BN / 64; ++h) {  // stage B tile BNx32
      int n = (t >> 2) + h * 64;
      uint4 v = *(const uint4*)(Bt + (size_t)n * K + k0 + akc);
      *(uint2*)&Bs[n][akc] = make_uint2(v.x, v.y);
      *(uint2*)&Bs[n][akc + 4] = make_uint2(v.z, v.w);
    }
    __syncthreads();
    short8 af[4], bfr[CF];
#pragma unroll
    for (int rf = 0; rf < 4; ++rf) {
      short4v lo = *(short4v*)&As[rf * 16 + c16][q * 8];
      short4v hi = *(short4v*)&As[rf * 16 + c16][q * 8 + 4];
      af[rf] = __builtin_shufflevector(lo, hi, 0, 1, 2, 3, 4, 5, 6, 7);
    }
#pragma unroll
    for (int cf = 0; cf < CF; ++cf) {
      int n = w * (CF * 16) + cf * 16 + c16;
      short4v lo = *(short4v*)&Bs[n][q * 8];
      short4v hi = *(short4v*)&Bs[n][q * 8 + 4];
      bfr[cf] = __builtin_shufflevector(lo, hi, 0, 1, 2, 3, 4, 5, 6, 7);
    }
#pragma unroll
    for (int rf = 0; rf < 4; ++rf)
#pragma unroll
      for (int cf = 0; cf < CF; ++cf)
        acc[rf][cf] =
            __builtin_amdgcn_mfma_f32_16x16x32_bf16(af[rf], bfr[cf], acc[rf][cf], 0, 0, 0);
    __syncthreads();
  }

  float sasv[CF], sadv[CF];
#pragma unroll
  for (int cf = 0; cf < CF; ++cf) {
    int L = w * (CF * 16) + cf * 16 + c16;
    sasv[cf] = a_s[L];
    sadv[cf] = a_d[L];
  }
  // slice-major store base: subtable = w*2 + (c16>>3)
  const size_t sub = (size_t)(w * 2 + (c16 >> 3)) * (size_t)M * SF;
#pragma unroll
  for (int rf = 0; rf < 4; ++rf) {
#pragma unroll
    for (int r = 0; r < 4; ++r) {
      int n = bm + rf * 16 + q * 4 + r;
      float ps = 0.f, pd = 0.f;
      unsigned short us[CF];
#pragma unroll
      for (int cf = 0; cf < CF; ++cf) {
        float v = acc[rf][cf][r];
        us[cf] = f2bf(v);
        ps += v * sasv[cf];
        pd += v * sadv[cf];
      }
#pragma unroll
      for (int off = 1; off <= 8; off <<= 1) {
        ps += __shfl_xor(ps, off, 16);
        pd += __shfl_xor(pd, off, 16);
      }
      if (n < M) {
        if constexpr (CF == 4) {
          ushort4 u;
          u.x = us[0]; u.y = us[1]; u.z = us[2]; u.w = us[3];
          *(ushort4*)(hout + sub + (size_t)n * 32 + (c16 & 7) * 4) = u;
        } else {
          ushort2 u;
          u.x = us[0]; u.y = us[1];
          *(ushort2*)(hout + sub + (size_t)n * 16 + (c16 & 7) * 2) = u;
        }
        if (c16 == 0) {
          als[(size_t)n * 4 + w] = ps;
          ald[(size_t)n * 4 + w] = pd;
        }
      }
    }
  }
}

// ---------------- XCD-sliced GAT agg, staged-exp edges, fused softmax -------
// D==256: 8 slices (32 cols), slot=blockIdx&7=slice, 32 nodes/block.
// D==128: 4 slices (32 cols, slice=head); 8 XCD slots = (head, node-half),
//         so each XCD touches exactly one head's 3.2MB subtable pair.
// Staging computes s_a[i] = exp(leaky(als[s]+ald[dst(i)])) ONCE per edge
// (dst via 5-step binary search on LDS row bounds); hot loop is pure
// gather-FMA + ssum. Epilogue: normalize, folded BN, ELU, nt store.

template <int D>
__global__ __launch_bounds__(256) void gat_agg_slice(
    const unsigned short* __restrict__ h_sl,  // 8 slice-major subtables
    const float* __restrict__ als, const float* __restrict__ ald,  // [N][4]
    const int* __restrict__ row_start, const int* __restrict__ csr_src,
    const float* __restrict__ bnsc, const float* __restrict__ bnsh,  // [D] logical
    unsigned short* __restrict__ obf,  // D==256 out (bf16 phys rows)
    float* __restrict__ of32,          // D==128 out (f32 phys rows)
    int n_nodes) {
  constexpr int CAP = 1280;  // staged edges (mean 544, +32 sigma)
  __shared__ int s_s[CAP];
  __shared__ float s_a[CAP];
  __shared__ int rb[33];
  const int slot = blockIdx.x & 7;
  const int g = blockIdx.x >> 3;
  const int tid = threadIdx.x;
  const int wid = tid >> 6, lane = tid & 63;
  const int f = lane & 7;    // feat slot
  const int ng = lane >> 3;  // node sub-slot 0..7
  const int hd = (D == 256) ? (slot >> 1) : (slot >> 1);  // head
  const int nb0 = (D == 256) ? (g * 32) : (g * 64 + (slot & 1) * 32);

  // per-lane h base pointer
  const unsigned short* hbl;
  if constexpr (D == 256) {
    // slice = slot: subtable slot (32 cols), lane covers cols f*4..f*4+3
    hbl = h_sl + (size_t)slot * (size_t)(unsigned)n_nodes * 32 + f * 4;
  } else {
    // slice = head hd: subtables {2hd, 2hd+1} (16 cols each); lane f:
    // subtable 2hd+(f>>2), cols (f&3)*4..+3
    hbl = h_sl + (size_t)(hd * 2 + (f >> 2)) * (size_t)(unsigned)n_nodes * 16 +
          (f & 3) * 4;
  }

  // row bounds for this block's 32 nodes
  if (tid < 33) rb[tid] = row_start[min(nb0 + tid, n_nodes)];
  __syncthreads();
  const int rs = __builtin_amdgcn_readfirstlane(rb[0]);
  const int re = __builtin_amdgcn_readfirstlane(rb[32]);
  const bool fast = (re - rs) <= CAP;
  if (fast) {
    for (int i = rs + tid; i < re; i += 256) {
      int s = csr_src[i];
      // binary search: largest nd with rb[nd] <= i
      int lo = 0;
#pragma unroll
      for (int st = 16; st >= 1; st >>= 1) lo += (i >= rb[lo + st]) ? st : 0;
      float av = als[(size_t)(unsigned)s * 4 + hd] +
                 ald[(size_t)(unsigned)(nb0 + lo) * 4 + hd];
      av = fmaxf(av, 0.2f * av);
      s_s[i - rs] = s;
      s_a[i - rs] = __expf(av);
    }
  }
  __syncthreads();

  // folded BN constants for this lane's logical cols
  float scv[4], shv[4];
  if constexpr (D == 256) {
    const int lb = hd * 64 + (slot & 1) * 8 + f;
#pragma unroll
    for (int k = 0; k < 4; ++k) {
      scv[k] = bnsc[lb + k * 16];
      shv[k] = bnsh[lb + k * 16];
    }
  } else {
#pragma unroll
    for (int k = 0; k < 4; ++k) {
      int pin = f * 4 + k;  // col within head block
      int l = hd * 32 + (pin >> 4) * 8 + ((pin & 15) >> 1) + (pin & 1) * 16;
      scv[k] = bnsc[l];
      shv[k] = bnsh[l];
    }
  }

  int n = nb0 + wid * 8 + ng;
  bool valid = n < n_nodes;
  int row = valid ? row_start[n] : rs;
  int deg = valid ? (row_start[n + 1] - row) : 0;
  int mx = deg;
#pragma unroll
  for (int off = 8; off <= 32; off <<= 1) mx = max(mx, __shfl_xor(mx, off, 64));
  mx = __builtin_amdgcn_readfirstlane(mx);

  float acc0 = 0.f, acc1 = 0.f, acc2 = 0.f, acc3 = 0.f, ssum = 0.f;

  if (fast) {
    int base = row - rs;
#pragma unroll 4
    for (int j = 0; j < mx; ++j) {
      bool act = j < deg;
      int idx = base + (act ? j : 0);
      int s = s_s[idx];
      float ex = s_a[idx];
      ex = act ? ex : 0.f;
      ssum += ex;
      uint2v u = *(const uint2v*)(hbl + (size_t)(unsigned)s * (D == 256 ? 32 : 16));
      acc0 += ex * __uint_as_float(u.x << 16);
      acc1 += ex * __uint_as_float(u.x & 0xffff0000u);
      acc2 += ex * __uint_as_float(u.y << 16);
      acc3 += ex * __uint_as_float(u.y & 0xffff0000u);
    }
  } else {  // rare fallback: global reads + inline exp
    float aldv = ald[(size_t)(unsigned)(valid ? n : 0) * 4 + hd];
#pragma unroll 2
    for (int j = 0; j < mx; ++j) {
      bool act = j < deg;
      int idx = row + (act ? j : 0);
      int s = csr_src[idx];
      float av = als[(size_t)(unsigned)s * 4 + hd] + aldv;
      av = fmaxf(av, 0.2f * av);
      float ex = __expf(av);
      ex = act ? ex : 0.f;
      ssum += ex;
      uint2v u = *(const uint2v*)(hbl + (size_t)(unsigned)s * (D == 256 ? 32 : 16));
      acc0 += ex * __uint_as_float(u.x << 16);
      acc1 += ex * __uint_as_float(u.x & 0xffff0000u);
      acc2 += ex * __uint_as_float(u.y << 16);
      acc3 += ex * __uint_as_float(u.y & 0xffff0000u);
    }
  }

  if (valid) {
    float inv = 1.f / (ssum + 1e-16f);
    float v0 = (acc0 * inv) * scv[0] + shv[0];
    float v1 = (acc1 * inv) * scv[1] + shv[1];
    float v2 = (acc2 * inv) * scv[2] + shv[2];
    float v3 = (acc3 * inv) * scv[3] + shv[3];
    v0 = (v0 > 0.f) ? v0 : (__expf(v0) - 1.f);
    v1 = (v1 > 0.f) ? v1 : (__expf(v1) - 1.f);
    v2 = (v2 > 0.f) ? v2 : (__expf(v2) - 1.f);
    v3 = (v3 > 0.f) ? v3 : (__expf(v3) - 1.f);
    if constexpr (D == 256) {
      uint2v pk;
      pk.x = (unsigned)f2bf(v0) | ((unsigned)f2bf(v1) << 16);
      pk.y = (unsigned)f2bf(v2) | ((unsigned)f2bf(v3) << 16);
      __builtin_nontemporal_store(
          pk, (uint2v*)(obf + (size_t)n * 256 + slot * 32 + f * 4));
    } else {
      f4v v4;
      v4.x = v0; v4.y = v1; v4.z = v2; v4.w = v3;
      __builtin_nontemporal_store(
          v4, (f4v*)(of32 + (size_t)n * 128 + hd * 32 + f * 4));
    }
  }
}

// ---------------- layer-3 prep: h3 = o2 @ W3, als3/ald3 ---------------------

__global__ __launch_bounds__(256) void l3_prep_kernel(
    const float* __restrict__ o2, const float* __restrict__ W3,
    const float* __restrict__ a3s, const float* __restrict__ a3d,
    float4* __restrict__ h3p, float* __restrict__ ald3, int n_nodes) {
  __shared__ float w3s[384];
  __shared__ float sa3[6];
  for (int i = threadIdx.x; i < 384; i += 256) w3s[i] = W3[i];
  if (threadIdx.x < 3) {
    sa3[threadIdx.x] = a3s[threadIdx.x];
    sa3[3 + threadIdx.x] = a3d[threadIdx.x];
  }
  __syncthreads();
  int wid = threadIdx.x >> 6, lane = threadIdx.x & 63;
  int n = blockIdx.x * 4 + wid;
  if (n >= n_nodes) return;
  f2v v = *(const f2v*)(o2 + (size_t)n * 128 + lane * 2);  // phys cols lane*2,+1
  int hd = lane >> 4;
  int k0l = hd * 32 + (lane & 15);  // logical k of phys col lane*2
  int k1l = k0l + 16;               // logical k of phys col lane*2+1
  float p0 = v.x * w3s[k0l * 3 + 0] + v.y * w3s[k1l * 3 + 0];
  float p1 = v.x * w3s[k0l * 3 + 1] + v.y * w3s[k1l * 3 + 1];
  float p2 = v.x * w3s[k0l * 3 + 2] + v.y * w3s[k1l * 3 + 2];
#pragma unroll
  for (int off = 32; off >= 1; off >>= 1) {
    p0 += __shfl_xor(p0, off, 64);
    p1 += __shfl_xor(p1, off, 64);
    p2 += __shfl_xor(p2, off, 64);
  }
  if (lane == 0) {
    float als3 = p0 * sa3[0] + p1 * sa3[1] + p2 * sa3[2];
    float ad3 = p0 * sa3[3] + p1 * sa3[4] + p2 * sa3[5];
    h3p[n] = make_float4(p0, p1, p2, als3);
    ald3[n] = ad3;
  }
}

// ---------------- layer 3 aggregation + log_softmax -------------------------

__global__ __launch_bounds__(256) void l3_agg_kernel(const float4* __restrict__ h3p,
                                                     const float* __restrict__ ald3,
                                                     const int* __restrict__ row_start,
                                                     const int* __restrict__ csr_src,
                                                     const float* __restrict__ b3,
                                                     float* __restrict__ out, int n_nodes) {
  int wid = threadIdx.x >> 6, lane = threadIdx.x & 63;
  int n = __builtin_amdgcn_readfirstlane(blockIdx.x * 4 + wid);
  if (n >= n_nodes) return;
  float aldv = ald3[n];
  int row = __builtin_amdgcn_readfirstlane(row_start[n]);
  int end = __builtin_amdgcn_readfirstlane(row_start[n + 1]);
  const char* hp = (const char*)h3p;
  float a0 = 0.f, a1 = 0.f, a2 = 0.f, ss = 0.f;
  for (int i = row + lane; i < end; i += 64) {
    int s = csr_src[i];
    float4 hv = *(const float4*)(hp + ((unsigned)s * 16u));
    float e = hv.w + aldv;
    e = fmaxf(e, 0.2f * e);
    float ex = __expf(e);
    ss += ex;
    a0 += ex * hv.x;
    a1 += ex * hv.y;
    a2 += ex * hv.z;
  }
#pragma unroll
  for (int off = 32; off >= 1; off >>= 1) {
    a0 += __shfl_xor(a0, off, 64);
    a1 += __shfl_xor(a1, off, 64);
    a2 += __shfl_xor(a2, off, 64);
    ss += __shfl_xor(ss, off, 64);
  }
  if (lane == 0) {
    float inv = 1.f / (ss + 1e-16f);
    float o0 = a0 * inv + b3[0];
    float o1 = a1 * inv + b3[1];
    float o2 = a2 * inv + b3[2];
    float m = fmaxf(o0, fmaxf(o1, o2));
    float lse = m + logf(expf(o0 - m) + expf(o1 - m) + expf(o2 - m));
    out[n * 3 + 0] = o0 - lse;
    out[n * 3 + 1] = o1 - lse;
    out[n * 3 + 2] = o2 - lse;
  }
}

// ---------------------------------------------------------------------------

extern "C" void kernel_launch(void* const* d_in, const int* in_sizes, int n_in,
                              void* d_out, int out_size, void* d_ws, size_t ws_size,
                              hipStream_t stream) {
  const float* x   = (const float*)d_in[0];
  const int*   ei  = (const int*)d_in[1];
  const float* W1  = (const float*)d_in[2];
  const float* a1s = (const float*)d_in[3];
  const float* a1d = (const float*)d_in[4];
  const float* b1  = (const float*)d_in[5];
  const float* g1v = (const float*)d_in[6];
  const float* be1 = (const float*)d_in[7];
  const float* m1  = (const float*)d_in[8];
  const float* v1  = (const float*)d_in[9];
  const float* W2  = (const float*)d_in[10];
  const float* a2s = (const float*)d_in[11];
  const float* a2d = (const float*)d_in[12];
  const float* b2  = (const float*)d_in[13];
  const float* g2v = (const float*)d_in[14];
  const float* be2 = (const float*)d_in[15];
  const float* m2  = (const float*)d_in[16];
  const float* v2  = (const float*)d_in[17];
  const float* W3  = (const float*)d_in[18];
  const float* a3s = (const float*)d_in[19];
  const float* a3d = (const float*)d_in[20];
  const float* b3  = (const float*)d_in[21];
  float* out = (float*)d_out;

  const int N = in_sizes[0] / 128;  // 50000
  const int E = in_sizes[1] / 2;    // 850000
  const int* srcv = ei;
  const int* dstv = ei + E;

  const int eb = (E + 255) / 256;
  const int nb = (N + 1023) / 1024;
  const int nodes4 = (N + 3) / 4;
  const int mblocks = (N + 63) / 64;
  const int agg1blocks = ((N + 31) / 32) * 8;  // 32 nodes/block x 8 slices
  const int agg2blocks = ((N + 63) / 64) * 8;  // 64 nodes split x (head,half)

  // workspace carve-up (~60 MB)
  float* wsf  = (float*)d_ws;
  float* als1 = wsf;                   // N*4
  float* ald1 = als1 + (size_t)N * 4;
  float* als2 = ald1 + (size_t)N * 4;
  float* ald2 = als2 + (size_t)N * 4;
  float* h3p  = ald2 + (size_t)N * 4;  // N*4 (float4 rows)
  float* ald3 = h3p + (size_t)N * 4;   // N
  unsigned short* h1s   = (unsigned short*)(ald3 + N);  // N*256 (8 subtables N*32)
  unsigned short* o1_bf = h1s + (size_t)N * 256;        // N*256 row-major phys
  unsigned short* W1t   = o1_bf + (size_t)N * 256;      // 256*128
  unsigned short* W2t   = W1t + 256 * 128;              // 128*256
  int* deg       = (int*)(W2t + 128 * 256);  // N
  int* row_start = deg + N;                  // N+1
  int* cursor    = row_start + (N + 1);      // N+1
  int* csr_src   = cursor + (N + 1);         // E
  int* bsum      = csr_src + E;              // 1024
  float* bnsc1 = (float*)(bsum + 1024);      // 256
  float* bnsh1 = bnsc1 + 256;                // 256
  float* bnsc2 = bnsh1 + 256;                // 128
  float* bnsh2 = bnsc2 + 128;                // 128
  unsigned short* h2s = (unsigned short*)(bnsh2 + 128);  // N*128 (8 subtables N*16)
  // alias (lifetimes disjoint): o2 f32 reuses h1s (dead after agg1)
  float* o2f = (float*)h1s;  // N*128 f32

  // weight conversions + BN fold
  conv_w1t_kernel<<<128, 256, 0, stream>>>(W1, W1t);
  conv_w2t_kernel<<<128, 256, 0, stream>>>(W2, W2t);
  bn_prep_kernel<<<1, 512, 0, stream>>>(b1, g1v, be1, m1, v1, b2, g2v, be2, m2, v2,
                                        bnsc1, bnsh1, bnsc2, bnsh2);

  // CSR build (shared by all 3 layers)
  hipMemsetAsync(deg, 0, (size_t)N * sizeof(int), stream);
  hist_kernel<<<eb, 256, 0, stream>>>(dstv, E, deg);
  block_sums_kernel<<<nb, 256, 0, stream>>>(deg, N, bsum);
  tiny_scan_kernel<<<1, 64, 0, stream>>>(bsum, nb);
  scan_write_kernel<<<nb, 256, 0, stream>>>(deg, N, bsum, row_start, cursor);
  scatter_kernel<<<eb, 256, 0, stream>>>(srcv, dstv, E, cursor, csr_src);

  // layer 1
  gemm_mfma<128, 256, true><<<mblocks, 256, 0, stream>>>(x, W1t, a1s, a1d, h1s, als1,
                                                         ald1, N);
  gat_agg_slice<256><<<agg1blocks, 256, 0, stream>>>(
      h1s, als1, ald1, row_start, csr_src, bnsc1, bnsh1, o1_bf, nullptr, N);
  // layer 2
  gemm_mfma<256, 128, false><<<mblocks, 256, 0, stream>>>(o1_bf, W2t, a2s, a2d, h2s, als2,
                                                          ald2, N);
  gat_agg_slice<128><<<agg2blocks, 256, 0, stream>>>(
      h2s, als2, ald2, row_start, csr_src, bnsc2, bnsh2, nullptr, o2f, N);
  // layer 3 prep + aggregation + log_softmax
  l3_prep_kernel<<<nodes4, 256, 0, stream>>>(o2f, W3, a3s, a3d, (float4*)h3p, ald3, N);
  l3_agg_kernel<<<nodes4, 256, 0, stream>>>((const float4*)h3p, ald3, row_start, csr_src,
                                            b3, out, N);
}